// Round 8
// baseline (210.891 us; speedup 1.0000x reference)
//
#include <hip/hip_runtime.h>
#include <stdint.h>

// ---------- types ----------
typedef __bf16 bf16x8 __attribute__((ext_vector_type(8)));
typedef float  f32x4  __attribute__((ext_vector_type(4)));
typedef unsigned short u16x4 __attribute__((ext_vector_type(4)));

#define MFMA16(a,b,c) __builtin_amdgcn_mfma_f32_16x16x32_bf16((a),(b),(c),0,0,0)

constexpr int Bc  = 4;
constexpr int Tc  = 2048;
constexpr int Dc  = 768;
constexpr int Hc  = 12;
constexpr int NTOK = Bc * Tc;        // 8192
constexpr int QKV_LD = 3 * Dc;       // 2304

static __device__ __forceinline__ unsigned short f2bf(float f){
  unsigned u = __float_as_uint(f);
  u += 0x7fffu + ((u >> 16) & 1u);   // RNE
  return (unsigned short)(u >> 16);
}

static __device__ __forceinline__ float exp2a(float x){
  float r; asm("v_exp_f32 %0, %1" : "=v"(r) : "v"(x)); return r;
}

static __device__ __forceinline__ float max3f(float a, float b, float c){
  float r; asm("v_max3_f32 %0, %1, %2, %3" : "=v"(r) : "v"(a), "v"(b), "v"(c)); return r;
}

static __device__ __forceinline__ unsigned cvtpk_bf16(float lo, float hi){
  unsigned r; asm("v_cvt_pk_bf16_f32 %0, %1, %2" : "=v"(r) : "v"(lo), "v"(hi)); return r;
}

static __device__ __forceinline__ void gload_lds16(const void* g, void* l){
  __builtin_amdgcn_global_load_lds((__attribute__((address_space(1))) void*)g,
                                   (__attribute__((address_space(3))) void*)l,
                                   16, 0, 0);
}

// ---------- f32 -> bf16 conversion ----------
__global__ void cvt_bf16(const float* __restrict__ src, unsigned short* __restrict__ dst,
                         int n4, float scale){
  int i = blockIdx.x * blockDim.x + threadIdx.x;
  if (i >= n4) return;
  float4 v = reinterpret_cast<const float4*>(src)[i];
  ushort4 o;
  o.x = f2bf(v.x * scale); o.y = f2bf(v.y * scale);
  o.z = f2bf(v.z * scale); o.w = f2bf(v.w * scale);
  reinterpret_cast<ushort4*>(dst)[i] = o;
}

// ---------- mask expansion with layout auto-detection ----------
__global__ void expand_mask(const unsigned* __restrict__ raw, int* __restrict__ out, int n){
  __shared__ int sInt, sFlt;
  int t = threadIdx.x;
  if (t == 0){ sInt = 1; sFlt = 1; }
  __syncthreads();
  int okI = 1, okF = 1;
  for (int i = t; i < n/4; i += blockDim.x){
    unsigned u = raw[i];
    okI &= (u <= 1u);
    okF &= (u == 0u || u == 0x3f800000u);
  }
  if (!okI) atomicAnd(&sInt, 0);
  if (!okF) atomicAnd(&sFlt, 0);
  __syncthreads();
  if (sInt || sFlt){
    for (int i = t; i < n; i += blockDim.x) out[i] = (raw[i] != 0u);
  } else {
    const unsigned char* rb = (const unsigned char*)raw;
    for (int i = t; i < n; i += blockDim.x) out[i] = (rb[i] != 0);
  }
}

// ---------- bf16 NT GEMM (verified round 0) ----------
template<typename CT>
__global__ __launch_bounds__(256) void gemm_bt(const unsigned short* __restrict__ A,
                                               const unsigned short* __restrict__ Bm,
                                               CT* __restrict__ C,
                                               int M, int N, int K){
  __shared__ unsigned short As[128*32];
  __shared__ unsigned short Bs[128*32];
  const int t = threadIdx.x;
  const int w = t >> 6, l = t & 63;
  const int wr = w >> 1, wc = w & 1;
  const int br = blockIdx.y * 128, bc = blockIdx.x * 128;

  f32x4 acc[4][4];
  const f32x4 fz = {0.f,0.f,0.f,0.f};
  #pragma unroll
  for (int m=0;m<4;m++)
    #pragma unroll
    for (int n=0;n<4;n++) acc[m][n] = fz;

  const int lrow = l >> 2;
  const int lk   = (l & 3) * 8;
  const int fr   = l & 15;
  const int fk   = (l >> 4) * 8;

  for (int k0 = 0; k0 < K; k0 += 32){
    #pragma unroll
    for (int it = 0; it < 2; ++it){
      const int rb = it*64 + w*16;
      gload_lds16(A  + (size_t)(br + rb + lrow)*K + k0 + lk, &As[rb*32]);
      gload_lds16(Bm + (size_t)(bc + rb + lrow)*K + k0 + lk, &Bs[rb*32]);
    }
    __syncthreads();
    bf16x8 a[4], b[4];
    #pragma unroll
    for (int m=0;m<4;m++)
      a[m] = *reinterpret_cast<const bf16x8*>(&As[(wr*64 + m*16 + fr)*32 + fk]);
    #pragma unroll
    for (int n=0;n<4;n++)
      b[n] = *reinterpret_cast<const bf16x8*>(&Bs[(wc*64 + n*16 + fr)*32 + fk]);
    #pragma unroll
    for (int m=0;m<4;m++)
      #pragma unroll
      for (int n=0;n<4;n++)
        acc[m][n] = MFMA16(a[m], b[n], acc[m][n]);
    __syncthreads();
  }

  const int orow0 = br + wr*64 + (l >> 4)*4;
  const int ocol0 = bc + wc*64 + (l & 15);
  #pragma unroll
  for (int m=0;m<4;m++)
    #pragma unroll
    for (int n=0;n<4;n++)
      #pragma unroll
      for (int r=0;r<4;r++){
        const size_t idx = (size_t)(orow0 + m*16 + r) * N + (ocol0 + n*16);
        float v = acc[m][n][r];
        if constexpr (sizeof(CT) == 2) C[idx] = (CT)f2bf(v);
        else                           C[idx] = v;
      }
}

// ---------- V transpose: QKV V-region -> VtG[(b*H+h)*64 + d][T] ----------
__global__ __launch_bounds__(256) void vtrans(const unsigned short* __restrict__ QKV,
                                              unsigned short* __restrict__ VtG){
  __shared__ unsigned short st[64][72];   // padded rows
  const int t = threadIdx.x;
  const int token0 = blockIdx.x * 64;
  const int bh = blockIdx.y;
  const int b = bh / Hc, h = bh - b * Hc;
  const size_t tokbase = (size_t)b * Tc;

  const int tok = t >> 2;
  const unsigned short* src = QKV + (tokbase + token0 + tok) * (size_t)QKV_LD + 1536 + h*64;
  #pragma unroll
  for (int i = 0; i < 2; ++i){
    const int ul = (t & 3)*2 + i;
    *reinterpret_cast<uint4*>(&st[tok][ul*8]) =
        *reinterpret_cast<const uint4*>(src + ul*8);
  }
  __syncthreads();
  const int d = t >> 2;
  #pragma unroll
  for (int half = 0; half < 2; ++half){
    union { unsigned short s[8]; uint4 q; } tmp;
    const int tk0 = (t & 3)*8 + half*32;
    #pragma unroll
    for (int j = 0; j < 8; ++j)
      tmp.s[j] = st[tk0 + j][d];
    *reinterpret_cast<uint4*>(VtG + ((size_t)(bh*64 + d))*Tc + token0 + tk0) = tmp.q;
  }
}

// ---------- flash attention: Q-tile 64, 1536 blocks (4/CU), XCD swizzle ----------
// 4 waves x 16 q-rows; KV chunk = 64, 2 LDS buffers.
// Round-7 lesson: grid=768 was the occupancy cap (3 blocks/CU); double the
// block count so the 33KB-LDS limit of 4 blocks/CU is actually reachable.
__global__ __launch_bounds__(256, 4) void attn(const unsigned short* __restrict__ QKV,
                                               const unsigned short* __restrict__ VtG,
                                               const int* __restrict__ mask,
                                               unsigned short* __restrict__ AO){
  __shared__ unsigned short Ks[2][64*64];  // K chunk, source-swizzled (16B units: c ^= row&7)
  __shared__ unsigned short Vs[2][64*64];  // V^T chunk [d][key], same source swizzle
  __shared__ float Ms[2][64];              // additive key-mask bias

  const int t = threadIdx.x, w = t >> 6, l = t & 63;
  // bijective XCD swizzle: XCD x owns bh-range [x*6, x*6+6) -> K/V set 3MB < 4MB L2
  const int lin = blockIdx.y * gridDim.x + blockIdx.x;       // 0..1535
  const int swz = (lin & 7) * 192 + (lin >> 3);
  const int qt  = swz & 31;
  const int bh  = swz >> 5;
  const int b  = bh / Hc, h = bh - b * Hc;
  const int q0 = qt * 64 + w * 16;
  const int fr = l & 15, fg = l >> 4;

  const size_t tokbase = (size_t)b * Tc;
  const unsigned short* Qp = QKV + (tokbase + q0) * (size_t)QKV_LD + h*64;
  const unsigned short* Kbase = QKV + tokbase * (size_t)QKV_LD + h*64 + 768;
  const unsigned short* VtB = VtG + (size_t)(bh*64) * Tc;
  const int* bm = mask + b * Tc;

  // Q fragments: Q[q=fr][k=ks*32+fg*8+j]
  bf16x8 qa[2];
  #pragma unroll
  for (int ks=0; ks<2; ks++)
    qa[ks] = *reinterpret_cast<const bf16x8*>(
        Qp + (size_t)fr*QKV_LD + ks*32 + fg*8);

  // wave 0: preload all 32 chunk-mask bits for its lane's key slot
  unsigned bits = 0;
  if (w == 0){
    #pragma unroll
    for (int cc = 0; cc < 32; ++cc)
      bits |= (unsigned)(bm[cc*64 + l] != 0) << cc;
  }

  const f32x4 fz = {0.f,0.f,0.f,0.f};
  f32x4 accT[4];
  #pragma unroll
  for (int n=0; n<4; n++) accT[n] = fz;
  float mrow = -1e30f, lsum = 0.f;

  // ---- staging helper (4 gload_lds16 per thread per chunk, all waves) ----
  const int srow = l >> 3, scol = (l & 7) ^ (l >> 3);   // source swizzle
  auto stage = [&](int c){
    const int key0 = c * 64, buf = c & 1;
    #pragma unroll
    for (int i=0; i<2; i++){
      const int rb = w*16 + i*8;      // K rows
      gload_lds16(Kbase + (size_t)(key0 + rb + srow)*QKV_LD + scol*8,
                  &Ks[buf][rb*64]);
    }
    #pragma unroll
    for (int i=0; i<2; i++){
      const int rb = (w*2 + i)*8;     // V^T rows (d)
      gload_lds16(VtB + (size_t)(rb + srow)*Tc + key0 + scol*8,
                  &Vs[buf][rb*64]);
    }
  };

  // ---- prologue: stage chunk 0
  stage(0);
  if (w == 0) Ms[0][l] = (bits & 1u) ? -1e9f : 0.f;
  asm volatile("s_waitcnt vmcnt(0) lgkmcnt(0)" ::: "memory");
  __builtin_amdgcn_s_barrier();
  asm volatile("" ::: "memory");

  #pragma unroll 2
  for (int c = 0; c < 32; ++c){
    const int cb = c & 1;

    // ---- QK^T swapped: S^T[key][q], mask bias as C-init
    f32x4 S[4];
    __builtin_amdgcn_s_setprio(1);
    #pragma unroll
    for (int g=0; g<4; g++){
      S[g] = *reinterpret_cast<const f32x4*>(&Ms[cb][g*16 + fg*4]);
      #pragma unroll
      for (int ks=0; ks<2; ks++){
        const int row = g*16 + fr;
        bf16x8 kf = *reinterpret_cast<const bf16x8*>(
            &Ks[cb][row*64 + (((ks*4+fg) ^ (row&7))*8)]);
        S[g] = MFMA16(kf, qa[ks], S[g]);
      }
    }
    __builtin_amdgcn_s_setprio(0);

    // ---- issue stage(c+1): flies under softmax + PV (T14)
    if (c + 1 < 32) stage(c + 1);

    // ---- softmax(c): in-lane 16 keys (max3 tree) + 2 shfls; P packed in regs
    unsigned pkAll[4][2];
    {
      float a0 = max3f(S[0][0], S[0][1], S[0][2]);
      float a1 = max3f(S[0][3], S[1][0], S[1][1]);
      float a2 = max3f(S[1][2], S[1][3], S[2][0]);
      float a3 = max3f(S[2][1], S[2][2], S[2][3]);
      float a4 = max3f(S[3][0], S[3][1], S[3][2]);
      float cm = fmaxf(max3f(a0, a1, a2), max3f(a3, a4, S[3][3]));
      cm = fmaxf(cm, __shfl_xor(cm, 16));
      cm = fmaxf(cm, __shfl_xor(cm, 32));
      if (!__all(cm <= mrow + 8.0f)){     // defer-max (T13)
        const float nm = fmaxf(mrow, cm);
        const float sc = exp2a(mrow - nm);
        lsum *= sc;
        #pragma unroll
        for (int n=0; n<4; n++) accT[n] = accT[n] * sc;
        mrow = nm;
      }
      float ps = 0.f;
      #pragma unroll
      for (int g=0; g<4; g++){
        const float p0 = exp2a(S[g][0] - mrow);
        const float p1 = exp2a(S[g][1] - mrow);
        const float p2 = exp2a(S[g][2] - mrow);
        const float p3 = exp2a(S[g][3] - mrow);
        ps += (p0 + p1) + (p2 + p3);
        pkAll[g][0] = cvtpk_bf16(p0, p1);
        pkAll[g][1] = cvtpk_bf16(p2, p3);
      }
      ps += __shfl_xor(ps, 16);
      ps += __shfl_xor(ps, 32);
      lsum += ps;
    }

    // ---- PV swapped: O^T += V^T * P^T (permuted k-order, lane-local P)
    __builtin_amdgcn_s_setprio(1);
    #pragma unroll
    for (int ks2=0; ks2<2; ks2++){
      union PBu { unsigned u[4]; bf16x8 v; } pb;
      pb.u[0] = pkAll[ks2*2][0];   pb.u[1] = pkAll[ks2*2][1];
      pb.u[2] = pkAll[ks2*2+1][0]; pb.u[3] = pkAll[ks2*2+1][1];
      #pragma unroll
      for (int n=0; n<4; n++){
        const int row = n*16 + fr;
        union VA { u16x4 h[2]; bf16x8 v; } va;
        va.h[0] = *reinterpret_cast<const u16x4*>(
            &Vs[cb][row*64 + (((ks2*4     + (fg>>1)) ^ (row&7))*8) + (fg&1)*4]);
        va.h[1] = *reinterpret_cast<const u16x4*>(
            &Vs[cb][row*64 + (((ks2*4 + 2 + (fg>>1)) ^ (row&7))*8) + (fg&1)*4]);
        accT[n] = MFMA16(va.v, pb.v, accT[n]);
      }
    }
    __builtin_amdgcn_s_setprio(0);

    // ---- Ms(c+1) from register bits (no VMEM)
    if (w == 0 && c + 1 < 32)
      Ms[cb^1][l] = ((bits >> (c+1)) & 1u) ? -1e9f : 0.f;

    // ---- wait stage(c+1) landed + all LDS ops done, then barrier
    if (c < 31){
      asm volatile("s_waitcnt vmcnt(0) lgkmcnt(0)" ::: "memory");
      __builtin_amdgcn_s_barrier();
      asm volatile("" ::: "memory");
    }
  }

  // ---- epilogue: normalize, zero q-padded rows, packed 8B stores
  {
    const int qrow = q0 + fr;
    const int qm = bm[qrow];
    const float inv = (qm || lsum <= 0.f) ? 0.f : 1.f / lsum;
    #pragma unroll
    for (int n=0; n<4; n++){
      ushort4 o;
      o.x = f2bf(accT[n][0] * inv);
      o.y = f2bf(accT[n][1] * inv);
      o.z = f2bf(accT[n][2] * inv);
      o.w = f2bf(accT[n][3] * inv);
      *reinterpret_cast<ushort4*>(
          &AO[(tokbase + qrow) * (size_t)Dc + h*64 + n*16 + fg*4]) = o;
    }
  }
}

// ---------- launch ----------
extern "C" void kernel_launch(void* const* d_in, const int* in_sizes, int n_in,
                              void* d_out, int out_size, void* d_ws, size_t ws_size,
                              hipStream_t stream){
  const float* h    = (const float*)d_in[0];
  const unsigned* m = (const unsigned*)d_in[1];
  const float* Wq   = (const float*)d_in[2];
  const float* Wk   = (const float*)d_in[3];
  const float* Wv   = (const float*)d_in[4];
  const float* Wo   = (const float*)d_in[5];
  float* out        = (float*)d_out;

  unsigned short* hb   = (unsigned short*)d_ws;       // 8192*768 (reused as VtG after gemm1)
  unsigned short* Wqkv = hb   + (size_t)NTOK * Dc;    // 2304*768
  unsigned short* Wob  = Wqkv + (size_t)QKV_LD * Dc;  // 768*768
  unsigned short* QKV  = Wob  + (size_t)Dc * Dc;      // 8192*2304
  unsigned short* AO   = QKV  + (size_t)NTOK * QKV_LD;// 8192*768
  int* mexp            = (int*)(AO + (size_t)NTOK * Dc);

  const size_t need = ((size_t)NTOK*Dc + (size_t)QKV_LD*Dc + (size_t)Dc*Dc +
                       (size_t)NTOK*QKV_LD + (size_t)NTOK*Dc) * 2 + (size_t)NTOK*4;
  if (ws_size < need) return;

  const int W2 = Dc * Dc;
  // Wq folded with (1/8)*log2e -> scores in log2 domain for exp2 softmax
  cvt_bf16<<<(NTOK*Dc/4 + 255)/256, 256, 0, stream>>>(h,  hb,          NTOK*Dc/4, 1.0f);
  cvt_bf16<<<(W2/4 + 255)/256,      256, 0, stream>>>(Wq, Wqkv,        W2/4, 0.125f*1.44269504f);
  cvt_bf16<<<(W2/4 + 255)/256,      256, 0, stream>>>(Wk, Wqkv + W2,   W2/4, 1.0f);
  cvt_bf16<<<(W2/4 + 255)/256,      256, 0, stream>>>(Wv, Wqkv + 2*W2, W2/4, 1.0f);
  cvt_bf16<<<(W2/4 + 255)/256,      256, 0, stream>>>(Wo, Wob,         W2/4, 1.0f);
  expand_mask<<<1, 256, 0, stream>>>(m, mexp, NTOK);

  gemm_bt<unsigned short><<<dim3(QKV_LD/128, NTOK/128), 256, 0, stream>>>(
      hb, Wqkv, QKV, NTOK, QKV_LD, Dc);

  // V^T into the now-dead hb buffer
  unsigned short* VtG = hb;
  vtrans<<<dim3(Tc/64, Bc*Hc), 256, 0, stream>>>(QKV, VtG);

  attn<<<dim3(32, Bc*Hc), 256, 0, stream>>>(QKV, VtG, mexp, AO);

  gemm_bt<float><<<dim3(Dc/128, NTOK/128), 256, 0, stream>>>(
      AO, Wob, out, NTOK, Dc, Dc);
}

// Round 9
// 185.903 us; speedup vs baseline: 1.1344x; 1.1344x over previous
//
#include <hip/hip_runtime.h>
#include <stdint.h>

// ---------- types ----------
typedef __bf16 bf16x8 __attribute__((ext_vector_type(8)));
typedef float  f32x4  __attribute__((ext_vector_type(4)));
typedef float  f32x16 __attribute__((ext_vector_type(16)));
typedef unsigned short u16x4 __attribute__((ext_vector_type(4)));

#define MFMA16(a,b,c) __builtin_amdgcn_mfma_f32_16x16x32_bf16((a),(b),(c),0,0,0)
#define MFMA32(a,b,c) __builtin_amdgcn_mfma_f32_32x32x16_bf16((a),(b),(c),0,0,0)

constexpr int Bc  = 4;
constexpr int Tc  = 2048;
constexpr int Dc  = 768;
constexpr int Hc  = 12;
constexpr int NTOK = Bc * Tc;        // 8192
constexpr int QKV_LD = 3 * Dc;       // 2304

static __device__ __forceinline__ unsigned short f2bf(float f){
  unsigned u = __float_as_uint(f);
  u += 0x7fffu + ((u >> 16) & 1u);   // RNE
  return (unsigned short)(u >> 16);
}

static __device__ __forceinline__ float exp2a(float x){
  float r; asm("v_exp_f32 %0, %1" : "=v"(r) : "v"(x)); return r;
}

static __device__ __forceinline__ float max3f(float a, float b, float c){
  float r; asm("v_max3_f32 %0, %1, %2, %3" : "=v"(r) : "v"(a), "v"(b), "v"(c)); return r;
}

static __device__ __forceinline__ unsigned cvtpk_bf16(float lo, float hi){
  unsigned r; asm("v_cvt_pk_bf16_f32 %0, %1, %2" : "=v"(r) : "v"(lo), "v"(hi)); return r;
}

static __device__ __forceinline__ void gload_lds16(const void* g, void* l){
  __builtin_amdgcn_global_load_lds((__attribute__((address_space(1))) void*)g,
                                   (__attribute__((address_space(3))) void*)l,
                                   16, 0, 0);
}

// ---------- f32 -> bf16 conversion ----------
__global__ void cvt_bf16(const float* __restrict__ src, unsigned short* __restrict__ dst,
                         int n4, float scale){
  int i = blockIdx.x * blockDim.x + threadIdx.x;
  if (i >= n4) return;
  float4 v = reinterpret_cast<const float4*>(src)[i];
  ushort4 o;
  o.x = f2bf(v.x * scale); o.y = f2bf(v.y * scale);
  o.z = f2bf(v.z * scale); o.w = f2bf(v.w * scale);
  reinterpret_cast<ushort4*>(dst)[i] = o;
}

// ---------- mask expansion with layout auto-detection ----------
__global__ void expand_mask(const unsigned* __restrict__ raw, int* __restrict__ out, int n){
  __shared__ int sInt, sFlt;
  int t = threadIdx.x;
  if (t == 0){ sInt = 1; sFlt = 1; }
  __syncthreads();
  int okI = 1, okF = 1;
  for (int i = t; i < n/4; i += blockDim.x){
    unsigned u = raw[i];
    okI &= (u <= 1u);
    okF &= (u == 0u || u == 0x3f800000u);
  }
  if (!okI) atomicAnd(&sInt, 0);
  if (!okF) atomicAnd(&sFlt, 0);
  __syncthreads();
  if (sInt || sFlt){
    for (int i = t; i < n; i += blockDim.x) out[i] = (raw[i] != 0u);
  } else {
    const unsigned char* rb = (const unsigned char*)raw;
    for (int i = t; i < n; i += blockDim.x) out[i] = (rb[i] != 0);
  }
}

// ---------- bf16 NT GEMM (verified round 0) ----------
template<typename CT>
__global__ __launch_bounds__(256) void gemm_bt(const unsigned short* __restrict__ A,
                                               const unsigned short* __restrict__ Bm,
                                               CT* __restrict__ C,
                                               int M, int N, int K){
  __shared__ unsigned short As[128*32];
  __shared__ unsigned short Bs[128*32];
  const int t = threadIdx.x;
  const int w = t >> 6, l = t & 63;
  const int wr = w >> 1, wc = w & 1;
  const int br = blockIdx.y * 128, bc = blockIdx.x * 128;

  f32x4 acc[4][4];
  const f32x4 fz = {0.f,0.f,0.f,0.f};
  #pragma unroll
  for (int m=0;m<4;m++)
    #pragma unroll
    for (int n=0;n<4;n++) acc[m][n] = fz;

  const int lrow = l >> 2;
  const int lk   = (l & 3) * 8;
  const int fr   = l & 15;
  const int fk   = (l >> 4) * 8;

  for (int k0 = 0; k0 < K; k0 += 32){
    #pragma unroll
    for (int it = 0; it < 2; ++it){
      const int rb = it*64 + w*16;
      gload_lds16(A  + (size_t)(br + rb + lrow)*K + k0 + lk, &As[rb*32]);
      gload_lds16(Bm + (size_t)(bc + rb + lrow)*K + k0 + lk, &Bs[rb*32]);
    }
    __syncthreads();
    bf16x8 a[4], b[4];
    #pragma unroll
    for (int m=0;m<4;m++)
      a[m] = *reinterpret_cast<const bf16x8*>(&As[(wr*64 + m*16 + fr)*32 + fk]);
    #pragma unroll
    for (int n=0;n<4;n++)
      b[n] = *reinterpret_cast<const bf16x8*>(&Bs[(wc*64 + n*16 + fr)*32 + fk]);
    #pragma unroll
    for (int m=0;m<4;m++)
      #pragma unroll
      for (int n=0;n<4;n++)
        acc[m][n] = MFMA16(a[m], b[n], acc[m][n]);
    __syncthreads();
  }

  const int orow0 = br + wr*64 + (l >> 4)*4;
  const int ocol0 = bc + wc*64 + (l & 15);
  #pragma unroll
  for (int m=0;m<4;m++)
    #pragma unroll
    for (int n=0;n<4;n++)
      #pragma unroll
      for (int r=0;r<4;r++){
        const size_t idx = (size_t)(orow0 + m*16 + r) * N + (ocol0 + n*16);
        float v = acc[m][n][r];
        if constexpr (sizeof(CT) == 2) C[idx] = (CT)f2bf(v);
        else                           C[idx] = v;
      }
}

// ---------- V transpose: QKV V-region -> VtG[(b*H+h)*64 + d][T] ----------
__global__ __launch_bounds__(256) void vtrans(const unsigned short* __restrict__ QKV,
                                              unsigned short* __restrict__ VtG){
  __shared__ unsigned short st[64][72];   // padded rows
  const int t = threadIdx.x;
  const int token0 = blockIdx.x * 64;
  const int bh = blockIdx.y;
  const int b = bh / Hc, h = bh - b * Hc;
  const size_t tokbase = (size_t)b * Tc;

  const int tok = t >> 2;
  const unsigned short* src = QKV + (tokbase + token0 + tok) * (size_t)QKV_LD + 1536 + h*64;
  #pragma unroll
  for (int i = 0; i < 2; ++i){
    const int ul = (t & 3)*2 + i;
    *reinterpret_cast<uint4*>(&st[tok][ul*8]) =
        *reinterpret_cast<const uint4*>(src + ul*8);
  }
  __syncthreads();
  const int d = t >> 2;
  #pragma unroll
  for (int half = 0; half < 2; ++half){
    union { unsigned short s[8]; uint4 q; } tmp;
    const int tk0 = (t & 3)*8 + half*32;
    #pragma unroll
    for (int j = 0; j < 8; ++j)
      tmp.s[j] = st[tk0 + j][d];
    *reinterpret_cast<uint4*>(VtG + ((size_t)(bh*64 + d))*Tc + token0 + tk0) = tmp.q;
  }
}

// ---------- flash attention: 32x32 MFMA, Q=128/block, 2-buffer, XCD swizzle ----------
// 4 waves x 32 q-rows each (one q per lane-column). KV chunk = 64.
// QK swapped (S^T), C layout: col=q=l&31, row=key=(r&3)+8*(r>>2)+4*(l>>5).
// P->B-operand is identity in C-reg order (slot j of k-slice ss = C-reg ss*8+j);
// V^T is read with the matching sigma key permutation (two b64 runs of 4).
__global__ __launch_bounds__(256, 3) void attn(const unsigned short* __restrict__ QKV,
                                               const unsigned short* __restrict__ VtG,
                                               const int* __restrict__ mask,
                                               unsigned short* __restrict__ AO){
  __shared__ unsigned short Ks[2][64*64];  // K chunk, source-swizzled (16B units: c ^= row&7)
  __shared__ unsigned short Vs[2][64*64];  // V^T chunk [d][key], same source swizzle
  __shared__ float Ms[2][64];              // additive key-mask bias

  const int t = threadIdx.x, w = t >> 6, l = t & 63;
  // bijective XCD swizzle over 768 blocks: XCD x owns bh in [6x,6x+6) -> 3MB L2 set
  const int lin = blockIdx.y * gridDim.x + blockIdx.x;   // 0..767
  const int swz = (lin & 7) * 96 + (lin >> 3);
  const int qt  = swz & 15;
  const int bh  = swz >> 4;
  const int b  = bh / Hc, h = bh - b * Hc;
  const int lq = l & 31, hi = l >> 5;
  const int q0w = qt * 128 + w * 32;

  const size_t tokbase = (size_t)b * Tc;
  const unsigned short* Qp = QKV + (tokbase + q0w) * (size_t)QKV_LD + h*64;
  const unsigned short* Kbase = QKV + tokbase * (size_t)QKV_LD + h*64 + 768;
  const unsigned short* VtB = VtG + (size_t)(bh*64) * Tc;
  const int* bm = mask + b * Tc;

  // Q B-operand frags: qa[s][j] = Q[q0w+lq][s*16 + hi*8 + j], s=0..3
  bf16x8 qa[4];
  #pragma unroll
  for (int s=0; s<4; s++)
    qa[s] = *reinterpret_cast<const bf16x8*>(
        Qp + (size_t)lq*QKV_LD + s*16 + hi*8);

  // wave 0: preload all 32 chunk-mask bits for its lane's key slot
  unsigned bits = 0;
  if (w == 0){
    #pragma unroll
    for (int cc = 0; cc < 32; ++cc)
      bits |= (unsigned)(bm[cc*64 + l] != 0) << cc;
  }

  f32x16 accO[2];
  #pragma unroll
  for (int dg=0; dg<2; dg++)
    #pragma unroll
    for (int r=0; r<16; r++) accO[dg][r] = 0.f;
  float mrow = -1e30f, lsum = 0.f;

  // ---- staging helper (4 gload_lds16 per thread per chunk) ----
  const int srow = l >> 3, scol = (l & 7) ^ (l >> 3);   // source swizzle
  auto stage = [&](int c){
    const int key0 = c * 64, buf = c & 1;
    #pragma unroll
    for (int i=0; i<2; i++){
      const int rb = w*16 + i*8;      // K rows
      gload_lds16(Kbase + (size_t)(key0 + rb + srow)*QKV_LD + scol*8,
                  &Ks[buf][rb*64]);
    }
    #pragma unroll
    for (int i=0; i<2; i++){
      const int rb = (w*2 + i)*8;     // V^T rows (d)
      gload_lds16(VtB + (size_t)(rb + srow)*Tc + key0 + scol*8,
                  &Vs[buf][rb*64]);
    }
  };

  // ---- prologue: stage chunk 0
  stage(0);
  if (w == 0) Ms[0][l] = (bits & 1u) ? -1e9f : 0.f;
  asm volatile("s_waitcnt vmcnt(0) lgkmcnt(0)" ::: "memory");
  __builtin_amdgcn_s_barrier();
  asm volatile("" ::: "memory");

  #pragma unroll 2
  for (int c = 0; c < 32; ++c){
    const int cb = c & 1;

    // ---- QK^T swapped (32x32x16): S[g] covers keys [32g,32g+32), cols = q
    f32x16 S[2];
    __builtin_amdgcn_s_setprio(1);
    #pragma unroll
    for (int g=0; g<2; g++){
      union { f32x4 q[4]; f32x16 v; } mi;
      #pragma unroll
      for (int m=0; m<4; m++)   // C-reg r=4m+e -> key 32g + 8m + e + 4hi
        mi.q[m] = *reinterpret_cast<const f32x4*>(&Ms[cb][g*32 + m*8 + hi*4]);
      S[g] = mi.v;
      #pragma unroll
      for (int s=0; s<4; s++){
        const int row = g*32 + lq;
        bf16x8 kf = *reinterpret_cast<const bf16x8*>(
            &Ks[cb][row*64 + (((2*s + hi) ^ (row&7))*8)]);
        S[g] = MFMA32(kf, qa[s], S[g]);
      }
    }
    __builtin_amdgcn_s_setprio(0);

    // ---- issue stage(c+1): flies under softmax + PV
    if (c + 1 < 32) stage(c + 1);

    // ---- softmax: 32 scores in-lane, ONE shfl per reduce
    unsigned pk[2][2][4];     // [g][ss][word] -> PV B-operand
    {
      float m0 = max3f(S[0][0],  S[0][1],  S[0][2]);
      float m1 = max3f(S[0][3],  S[0][4],  S[0][5]);
      float m2 = max3f(S[0][6],  S[0][7],  S[0][8]);
      float m3 = max3f(S[0][9],  S[0][10], S[0][11]);
      float m4 = max3f(S[0][12], S[0][13], S[0][14]);
      float m5 = max3f(S[0][15], S[1][0],  S[1][1]);
      float m6 = max3f(S[1][2],  S[1][3],  S[1][4]);
      float m7 = max3f(S[1][5],  S[1][6],  S[1][7]);
      float m8 = max3f(S[1][8],  S[1][9],  S[1][10]);
      float m9 = max3f(S[1][11], S[1][12], S[1][13]);
      float ma = fmaxf(S[1][14], S[1][15]);
      float cm = max3f(max3f(m0,m1,m2), max3f(m3,m4,m5),
                       max3f(max3f(m6,m7,m8), m9, ma));
      cm = fmaxf(cm, __shfl_xor(cm, 32));
      if (!__all(cm <= mrow + 8.0f)){     // defer-max (T13)
        const float nm = fmaxf(mrow, cm);
        const float sc = exp2a(mrow - nm);
        lsum *= sc;
        #pragma unroll
        for (int dg=0; dg<2; dg++)
          #pragma unroll
          for (int r=0; r<16; r++) accO[dg][r] *= sc;
        mrow = nm;
      }
      float ps = 0.f;
      #pragma unroll
      for (int g=0; g<2; g++){
        float p[16];
        #pragma unroll
        for (int r=0; r<16; r++) p[r] = exp2a(S[g][r] - mrow);
        float t0 = (p[0]+p[1]) + (p[2]+p[3]);
        float t1 = (p[4]+p[5]) + (p[6]+p[7]);
        float t2 = (p[8]+p[9]) + (p[10]+p[11]);
        float t3 = (p[12]+p[13]) + (p[14]+p[15]);
        ps += (t0+t1) + (t2+t3);
        #pragma unroll
        for (int ss=0; ss<2; ss++)
          #pragma unroll
          for (int j2=0; j2<4; j2++)
            pk[g][ss][j2] = cvtpk_bf16(p[ss*8 + 2*j2], p[ss*8 + 2*j2 + 1]);
      }
      ps += __shfl_xor(ps, 32);
      lsum += ps;
    }

    // ---- PV swapped (32x32x16): O^T[dg] += V^T * P^T, sigma key order
    __builtin_amdgcn_s_setprio(1);
    #pragma unroll
    for (int g=0; g<2; g++){
      #pragma unroll
      for (int ss=0; ss<2; ss++){
        union { unsigned u[4]; bf16x8 v; } pb;
        pb.u[0] = pk[g][ss][0]; pb.u[1] = pk[g][ss][1];
        pb.u[2] = pk[g][ss][2]; pb.u[3] = pk[g][ss][3];
        const int u0 = 4*g + 2*ss;     // 16B-unit of key base 32g+16ss
        #pragma unroll
        for (int dg=0; dg<2; dg++){
          const int d = dg*32 + lq;
          union { u16x4 h[2]; bf16x8 v; } va;
          va.h[0] = *reinterpret_cast<const u16x4*>(
              &Vs[cb][d*64 + ((u0     ^ (d&7))*8) + hi*4]);
          va.h[1] = *reinterpret_cast<const u16x4*>(
              &Vs[cb][d*64 + (((u0+1) ^ (d&7))*8) + hi*4]);
          accO[dg] = MFMA32(va.v, pb.v, accO[dg]);
        }
      }
    }
    __builtin_amdgcn_s_setprio(0);

    // ---- Ms(c+1) from register bits (no VMEM)
    if (w == 0 && c + 1 < 32)
      Ms[cb^1][l] = ((bits >> (c+1)) & 1u) ? -1e9f : 0.f;

    // ---- wait stage(c+1) landed + all LDS ops done, then barrier
    if (c < 31){
      asm volatile("s_waitcnt vmcnt(0) lgkmcnt(0)" ::: "memory");
      __builtin_amdgcn_s_barrier();
      asm volatile("" ::: "memory");
    }
  }

  // ---- epilogue: normalize, zero q-padded rows, 8B stores
  {
    const int qrow = q0w + lq;
    const int qm = bm[qrow];
    const float inv = (qm || lsum <= 0.f) ? 0.f : 1.f / lsum;
    #pragma unroll
    for (int dg=0; dg<2; dg++)
      #pragma unroll
      for (int m=0; m<4; m++){
        ushort4 o;
        o.x = f2bf(accO[dg][4*m+0] * inv);
        o.y = f2bf(accO[dg][4*m+1] * inv);
        o.z = f2bf(accO[dg][4*m+2] * inv);
        o.w = f2bf(accO[dg][4*m+3] * inv);
        *reinterpret_cast<ushort4*>(
            &AO[(tokbase + qrow) * (size_t)Dc + h*64 + dg*32 + m*8 + hi*4]) = o;
      }
  }
}

// ---------- launch ----------
extern "C" void kernel_launch(void* const* d_in, const int* in_sizes, int n_in,
                              void* d_out, int out_size, void* d_ws, size_t ws_size,
                              hipStream_t stream){
  const float* h    = (const float*)d_in[0];
  const unsigned* m = (const unsigned*)d_in[1];
  const float* Wq   = (const float*)d_in[2];
  const float* Wk   = (const float*)d_in[3];
  const float* Wv   = (const float*)d_in[4];
  const float* Wo   = (const float*)d_in[5];
  float* out        = (float*)d_out;

  unsigned short* hb   = (unsigned short*)d_ws;       // 8192*768 (reused as VtG after gemm1)
  unsigned short* Wqkv = hb   + (size_t)NTOK * Dc;    // 2304*768
  unsigned short* Wob  = Wqkv + (size_t)QKV_LD * Dc;  // 768*768
  unsigned short* QKV  = Wob  + (size_t)Dc * Dc;      // 8192*2304
  unsigned short* AO   = QKV  + (size_t)NTOK * QKV_LD;// 8192*768
  int* mexp            = (int*)(AO + (size_t)NTOK * Dc);

  const size_t need = ((size_t)NTOK*Dc + (size_t)QKV_LD*Dc + (size_t)Dc*Dc +
                       (size_t)NTOK*QKV_LD + (size_t)NTOK*Dc) * 2 + (size_t)NTOK*4;
  if (ws_size < need) return;

  const int W2 = Dc * Dc;
  // Wq folded with (1/8)*log2e -> scores in log2 domain for exp2 softmax
  cvt_bf16<<<(NTOK*Dc/4 + 255)/256, 256, 0, stream>>>(h,  hb,          NTOK*Dc/4, 1.0f);
  cvt_bf16<<<(W2/4 + 255)/256,      256, 0, stream>>>(Wq, Wqkv,        W2/4, 0.125f*1.44269504f);
  cvt_bf16<<<(W2/4 + 255)/256,      256, 0, stream>>>(Wk, Wqkv + W2,   W2/4, 1.0f);
  cvt_bf16<<<(W2/4 + 255)/256,      256, 0, stream>>>(Wv, Wqkv + 2*W2, W2/4, 1.0f);
  cvt_bf16<<<(W2/4 + 255)/256,      256, 0, stream>>>(Wo, Wob,         W2/4, 1.0f);
  expand_mask<<<1, 256, 0, stream>>>(m, mexp, NTOK);

  gemm_bt<unsigned short><<<dim3(QKV_LD/128, NTOK/128), 256, 0, stream>>>(
      hb, Wqkv, QKV, NTOK, QKV_LD, Dc);

  // V^T into the now-dead hb buffer
  unsigned short* VtG = hb;
  vtrans<<<dim3(Tc/64, Bc*Hc), 256, 0, stream>>>(QKV, VtG);

  attn<<<dim3(16, Bc*Hc), 256, 0, stream>>>(QKV, VtG, mexp, AO);

  gemm_bt<float><<<dim3(Dc/128, NTOK/128), 256, 0, stream>>>(
      AO, Wob, out, NTOK, Dc, Dc);
}

// Round 10
// 178.799 us; speedup vs baseline: 1.1795x; 1.0397x over previous
//
#include <hip/hip_runtime.h>
#include <stdint.h>

// ---------- types ----------
typedef __bf16 bf16x8 __attribute__((ext_vector_type(8)));
typedef float  f32x4  __attribute__((ext_vector_type(4)));
typedef float  f32x16 __attribute__((ext_vector_type(16)));
typedef unsigned short u16x4 __attribute__((ext_vector_type(4)));

#define MFMA16(a,b,c) __builtin_amdgcn_mfma_f32_16x16x32_bf16((a),(b),(c),0,0,0)
#define MFMA32(a,b,c) __builtin_amdgcn_mfma_f32_32x32x16_bf16((a),(b),(c),0,0,0)

constexpr int Bc  = 4;
constexpr int Tc  = 2048;
constexpr int Dc  = 768;
constexpr int Hc  = 12;
constexpr int NTOK = Bc * Tc;        // 8192
constexpr int QKV_LD = 3 * Dc;       // 2304

static __device__ __forceinline__ unsigned short f2bf(float f){
  unsigned u = __float_as_uint(f);
  u += 0x7fffu + ((u >> 16) & 1u);   // RNE
  return (unsigned short)(u >> 16);
}

static __device__ __forceinline__ float exp2a(float x){
  float r; asm("v_exp_f32 %0, %1" : "=v"(r) : "v"(x)); return r;
}

static __device__ __forceinline__ float max3f(float a, float b, float c){
  float r; asm("v_max3_f32 %0, %1, %2, %3" : "=v"(r) : "v"(a), "v"(b), "v"(c)); return r;
}

static __device__ __forceinline__ unsigned cvtpk_bf16(float lo, float hi){
  unsigned r; asm("v_cvt_pk_bf16_f32 %0, %1, %2" : "=v"(r) : "v"(lo), "v"(hi)); return r;
}

static __device__ __forceinline__ void gload_lds16(const void* g, void* l){
  __builtin_amdgcn_global_load_lds((__attribute__((address_space(1))) void*)g,
                                   (__attribute__((address_space(3))) void*)l,
                                   16, 0, 0);
}

// ---------- f32 -> bf16 conversion (h) ----------
__global__ void cvt_bf16(const float* __restrict__ src, unsigned short* __restrict__ dst,
                         int n4, float scale){
  int i = blockIdx.x * blockDim.x + threadIdx.x;
  if (i >= n4) return;
  float4 v = reinterpret_cast<const float4*>(src)[i];
  ushort4 o;
  o.x = f2bf(v.x * scale); o.y = f2bf(v.y * scale);
  o.z = f2bf(v.z * scale); o.w = f2bf(v.w * scale);
  reinterpret_cast<ushort4*>(dst)[i] = o;
}

// ---------- fused weight conversion: Wq(scaled)/Wk/Wv -> Wqkv, Wo -> Wob ----------
__global__ void cvt_w4(const float* __restrict__ Wq, const float* __restrict__ Wk,
                       const float* __restrict__ Wv, const float* __restrict__ Wo,
                       unsigned short* __restrict__ Wqkv, unsigned short* __restrict__ Wob,
                       int n4, float qscale){
  const int y = blockIdx.y;
  const float* src = (y==0) ? Wq : (y==1) ? Wk : (y==2) ? Wv : Wo;
  unsigned short* dst = (y==3) ? Wob : Wqkv + (size_t)y * n4 * 4;
  const float scale = (y==0) ? qscale : 1.0f;
  int i = blockIdx.x * blockDim.x + threadIdx.x;
  if (i >= n4) return;
  float4 v = reinterpret_cast<const float4*>(src)[i];
  ushort4 o;
  o.x = f2bf(v.x * scale); o.y = f2bf(v.y * scale);
  o.z = f2bf(v.z * scale); o.w = f2bf(v.w * scale);
  reinterpret_cast<ushort4*>(dst)[i] = o;
}

// ---------- mask expansion with layout auto-detection ----------
__global__ void expand_mask(const unsigned* __restrict__ raw, int* __restrict__ out, int n){
  __shared__ int sInt, sFlt;
  int t = threadIdx.x;
  if (t == 0){ sInt = 1; sFlt = 1; }
  __syncthreads();
  int okI = 1, okF = 1;
  for (int i = t; i < n/4; i += blockDim.x){
    unsigned u = raw[i];
    okI &= (u <= 1u);
    okF &= (u == 0u || u == 0x3f800000u);
  }
  if (!okI) atomicAnd(&sInt, 0);
  if (!okF) atomicAnd(&sFlt, 0);
  __syncthreads();
  if (sInt || sFlt){
    for (int i = t; i < n; i += blockDim.x) out[i] = (raw[i] != 0u);
  } else {
    const unsigned char* rb = (const unsigned char*)raw;
    for (int i = t; i < n; i += blockDim.x) out[i] = (rb[i] != 0);
  }
}

// ---------- bf16 NT GEMM 128x128 (verified round 0) ----------
template<typename CT>
__global__ __launch_bounds__(256) void gemm_bt(const unsigned short* __restrict__ A,
                                               const unsigned short* __restrict__ Bm,
                                               CT* __restrict__ C,
                                               int M, int N, int K){
  __shared__ unsigned short As[128*32];
  __shared__ unsigned short Bs[128*32];
  const int t = threadIdx.x;
  const int w = t >> 6, l = t & 63;
  const int wr = w >> 1, wc = w & 1;
  const int br = blockIdx.y * 128, bc = blockIdx.x * 128;

  f32x4 acc[4][4];
  const f32x4 fz = {0.f,0.f,0.f,0.f};
  #pragma unroll
  for (int m=0;m<4;m++)
    #pragma unroll
    for (int n=0;n<4;n++) acc[m][n] = fz;

  const int lrow = l >> 2;
  const int lk   = (l & 3) * 8;
  const int fr   = l & 15;
  const int fk   = (l >> 4) * 8;

  for (int k0 = 0; k0 < K; k0 += 32){
    #pragma unroll
    for (int it = 0; it < 2; ++it){
      const int rb = it*64 + w*16;
      gload_lds16(A  + (size_t)(br + rb + lrow)*K + k0 + lk, &As[rb*32]);
      gload_lds16(Bm + (size_t)(bc + rb + lrow)*K + k0 + lk, &Bs[rb*32]);
    }
    __syncthreads();
    bf16x8 a[4], b[4];
    #pragma unroll
    for (int m=0;m<4;m++)
      a[m] = *reinterpret_cast<const bf16x8*>(&As[(wr*64 + m*16 + fr)*32 + fk]);
    #pragma unroll
    for (int n=0;n<4;n++)
      b[n] = *reinterpret_cast<const bf16x8*>(&Bs[(wc*64 + n*16 + fr)*32 + fk]);
    #pragma unroll
    for (int m=0;m<4;m++)
      #pragma unroll
      for (int n=0;n<4;n++)
        acc[m][n] = MFMA16(a[m], b[n], acc[m][n]);
    __syncthreads();
  }

  const int orow0 = br + wr*64 + (l >> 4)*4;
  const int ocol0 = bc + wc*64 + (l & 15);
  #pragma unroll
  for (int m=0;m<4;m++)
    #pragma unroll
    for (int n=0;n<4;n++)
      #pragma unroll
      for (int r=0;r<4;r++){
        const size_t idx = (size_t)(orow0 + m*16 + r) * N + (ocol0 + n*16);
        float v = acc[m][n][r];
        if constexpr (sizeof(CT) == 2) C[idx] = (CT)f2bf(v);
        else                           C[idx] = v;
      }
}

// ---------- bf16 NT GEMM 64x128 (for M-heavy, small-N: out-proj) ----------
// 768 blocks at N=768 -> 3 blocks/CU (vs 1.5 with the 128x128 tile).
__global__ __launch_bounds__(256) void gemm_bt64(const unsigned short* __restrict__ A,
                                                 const unsigned short* __restrict__ Bm,
                                                 float* __restrict__ C,
                                                 int M, int N, int K){
  __shared__ unsigned short As[64*32];
  __shared__ unsigned short Bs[128*32];
  const int t = threadIdx.x;
  const int w = t >> 6, l = t & 63;
  const int wr = w >> 1, wc = w & 1;
  const int br = blockIdx.y * 64, bc = blockIdx.x * 128;

  f32x4 acc[2][4];
  const f32x4 fz = {0.f,0.f,0.f,0.f};
  #pragma unroll
  for (int m=0;m<2;m++)
    #pragma unroll
    for (int n=0;n<4;n++) acc[m][n] = fz;

  const int lrow = l >> 2;
  const int lk   = (l & 3) * 8;
  const int fr   = l & 15;
  const int fk   = (l >> 4) * 8;

  for (int k0 = 0; k0 < K; k0 += 32){
    gload_lds16(A + (size_t)(br + w*16 + lrow)*K + k0 + lk, &As[(w*16)*32]);
    #pragma unroll
    for (int it = 0; it < 2; ++it){
      const int rb = it*64 + w*16;
      gload_lds16(Bm + (size_t)(bc + rb + lrow)*K + k0 + lk, &Bs[rb*32]);
    }
    __syncthreads();
    bf16x8 a[2], b[4];
    #pragma unroll
    for (int m=0;m<2;m++)
      a[m] = *reinterpret_cast<const bf16x8*>(&As[(wr*32 + m*16 + fr)*32 + fk]);
    #pragma unroll
    for (int n=0;n<4;n++)
      b[n] = *reinterpret_cast<const bf16x8*>(&Bs[(wc*64 + n*16 + fr)*32 + fk]);
    #pragma unroll
    for (int m=0;m<2;m++)
      #pragma unroll
      for (int n=0;n<4;n++)
        acc[m][n] = MFMA16(a[m], b[n], acc[m][n]);
    __syncthreads();
  }

  const int orow0 = br + wr*32 + (l >> 4)*4;
  const int ocol0 = bc + wc*64 + (l & 15);
  #pragma unroll
  for (int m=0;m<2;m++)
    #pragma unroll
    for (int n=0;n<4;n++)
      #pragma unroll
      for (int r=0;r<4;r++)
        C[(size_t)(orow0 + m*16 + r) * N + (ocol0 + n*16)] = acc[m][n][r];
}

// ---------- V transpose: QKV V-region -> VtG[(b*H+h)*64 + d][T] ----------
__global__ __launch_bounds__(256) void vtrans(const unsigned short* __restrict__ QKV,
                                              unsigned short* __restrict__ VtG){
  __shared__ unsigned short st[64][72];   // padded rows
  const int t = threadIdx.x;
  const int token0 = blockIdx.x * 64;
  const int bh = blockIdx.y;
  const int b = bh / Hc, h = bh - b * Hc;
  const size_t tokbase = (size_t)b * Tc;

  const int tok = t >> 2;
  const unsigned short* src = QKV + (tokbase + token0 + tok) * (size_t)QKV_LD + 1536 + h*64;
  #pragma unroll
  for (int i = 0; i < 2; ++i){
    const int ul = (t & 3)*2 + i;
    *reinterpret_cast<uint4*>(&st[tok][ul*8]) =
        *reinterpret_cast<const uint4*>(src + ul*8);
  }
  __syncthreads();
  const int d = t >> 2;
  #pragma unroll
  for (int half = 0; half < 2; ++half){
    union { unsigned short s[8]; uint4 q; } tmp;
    const int tk0 = (t & 3)*8 + half*32;
    #pragma unroll
    for (int j = 0; j < 8; ++j)
      tmp.s[j] = st[tk0 + j][d];
    *reinterpret_cast<uint4*>(VtG + ((size_t)(bh*64 + d))*Tc + token0 + tk0) = tmp.q;
  }
}

// ---------- flash attention: 32x32 MFMA, Q=128/block, 2-buffer, XCD swizzle ----------
// (verified round 9: 87.4us, MfmaUtil 25.5)
__global__ __launch_bounds__(256, 3) void attn(const unsigned short* __restrict__ QKV,
                                               const unsigned short* __restrict__ VtG,
                                               const int* __restrict__ mask,
                                               unsigned short* __restrict__ AO){
  __shared__ unsigned short Ks[2][64*64];  // K chunk, source-swizzled (16B units: c ^= row&7)
  __shared__ unsigned short Vs[2][64*64];  // V^T chunk [d][key], same source swizzle
  __shared__ float Ms[2][64];              // additive key-mask bias

  const int t = threadIdx.x, w = t >> 6, l = t & 63;
  const int lin = blockIdx.y * gridDim.x + blockIdx.x;   // 0..767
  const int swz = (lin & 7) * 96 + (lin >> 3);
  const int qt  = swz & 15;
  const int bh  = swz >> 4;
  const int b  = bh / Hc, h = bh - b * Hc;
  const int lq = l & 31, hi = l >> 5;
  const int q0w = qt * 128 + w * 32;

  const size_t tokbase = (size_t)b * Tc;
  const unsigned short* Qp = QKV + (tokbase + q0w) * (size_t)QKV_LD + h*64;
  const unsigned short* Kbase = QKV + tokbase * (size_t)QKV_LD + h*64 + 768;
  const unsigned short* VtB = VtG + (size_t)(bh*64) * Tc;
  const int* bm = mask + b * Tc;

  bf16x8 qa[4];
  #pragma unroll
  for (int s=0; s<4; s++)
    qa[s] = *reinterpret_cast<const bf16x8*>(
        Qp + (size_t)lq*QKV_LD + s*16 + hi*8);

  unsigned bits = 0;
  if (w == 0){
    #pragma unroll
    for (int cc = 0; cc < 32; ++cc)
      bits |= (unsigned)(bm[cc*64 + l] != 0) << cc;
  }

  f32x16 accO[2];
  #pragma unroll
  for (int dg=0; dg<2; dg++)
    #pragma unroll
    for (int r=0; r<16; r++) accO[dg][r] = 0.f;
  float mrow = -1e30f, lsum = 0.f;

  const int srow = l >> 3, scol = (l & 7) ^ (l >> 3);   // source swizzle
  auto stage = [&](int c){
    const int key0 = c * 64, buf = c & 1;
    #pragma unroll
    for (int i=0; i<2; i++){
      const int rb = w*16 + i*8;      // K rows
      gload_lds16(Kbase + (size_t)(key0 + rb + srow)*QKV_LD + scol*8,
                  &Ks[buf][rb*64]);
    }
    #pragma unroll
    for (int i=0; i<2; i++){
      const int rb = (w*2 + i)*8;     // V^T rows (d)
      gload_lds16(VtB + (size_t)(rb + srow)*Tc + key0 + scol*8,
                  &Vs[buf][rb*64]);
    }
  };

  stage(0);
  if (w == 0) Ms[0][l] = (bits & 1u) ? -1e9f : 0.f;
  asm volatile("s_waitcnt vmcnt(0) lgkmcnt(0)" ::: "memory");
  __builtin_amdgcn_s_barrier();
  asm volatile("" ::: "memory");

  #pragma unroll 2
  for (int c = 0; c < 32; ++c){
    const int cb = c & 1;

    f32x16 S[2];
    __builtin_amdgcn_s_setprio(1);
    #pragma unroll
    for (int g=0; g<2; g++){
      union { f32x4 q[4]; f32x16 v; } mi;
      #pragma unroll
      for (int m=0; m<4; m++)
        mi.q[m] = *reinterpret_cast<const f32x4*>(&Ms[cb][g*32 + m*8 + hi*4]);
      S[g] = mi.v;
      #pragma unroll
      for (int s=0; s<4; s++){
        const int row = g*32 + lq;
        bf16x8 kf = *reinterpret_cast<const bf16x8*>(
            &Ks[cb][row*64 + (((2*s + hi) ^ (row&7))*8)]);
        S[g] = MFMA32(kf, qa[s], S[g]);
      }
    }
    __builtin_amdgcn_s_setprio(0);

    if (c + 1 < 32) stage(c + 1);

    unsigned pk[2][2][4];
    {
      float m0 = max3f(S[0][0],  S[0][1],  S[0][2]);
      float m1 = max3f(S[0][3],  S[0][4],  S[0][5]);
      float m2 = max3f(S[0][6],  S[0][7],  S[0][8]);
      float m3 = max3f(S[0][9],  S[0][10], S[0][11]);
      float m4 = max3f(S[0][12], S[0][13], S[0][14]);
      float m5 = max3f(S[0][15], S[1][0],  S[1][1]);
      float m6 = max3f(S[1][2],  S[1][3],  S[1][4]);
      float m7 = max3f(S[1][5],  S[1][6],  S[1][7]);
      float m8 = max3f(S[1][8],  S[1][9],  S[1][10]);
      float m9 = max3f(S[1][11], S[1][12], S[1][13]);
      float ma = fmaxf(S[1][14], S[1][15]);
      float cm = max3f(max3f(m0,m1,m2), max3f(m3,m4,m5),
                       max3f(max3f(m6,m7,m8), m9, ma));
      cm = fmaxf(cm, __shfl_xor(cm, 32));
      if (!__all(cm <= mrow + 8.0f)){     // defer-max (T13)
        const float nm = fmaxf(mrow, cm);
        const float sc = exp2a(mrow - nm);
        lsum *= sc;
        #pragma unroll
        for (int dg=0; dg<2; dg++)
          #pragma unroll
          for (int r=0; r<16; r++) accO[dg][r] *= sc;
        mrow = nm;
      }
      float ps = 0.f;
      #pragma unroll
      for (int g=0; g<2; g++){
        float p[16];
        #pragma unroll
        for (int r=0; r<16; r++) p[r] = exp2a(S[g][r] - mrow);
        float t0 = (p[0]+p[1]) + (p[2]+p[3]);
        float t1 = (p[4]+p[5]) + (p[6]+p[7]);
        float t2 = (p[8]+p[9]) + (p[10]+p[11]);
        float t3 = (p[12]+p[13]) + (p[14]+p[15]);
        ps += (t0+t1) + (t2+t3);
        #pragma unroll
        for (int ss=0; ss<2; ss++)
          #pragma unroll
          for (int j2=0; j2<4; j2++)
            pk[g][ss][j2] = cvtpk_bf16(p[ss*8 + 2*j2], p[ss*8 + 2*j2 + 1]);
      }
      ps += __shfl_xor(ps, 32);
      lsum += ps;
    }

    __builtin_amdgcn_s_setprio(1);
    #pragma unroll
    for (int g=0; g<2; g++){
      #pragma unroll
      for (int ss=0; ss<2; ss++){
        union { unsigned u[4]; bf16x8 v; } pb;
        pb.u[0] = pk[g][ss][0]; pb.u[1] = pk[g][ss][1];
        pb.u[2] = pk[g][ss][2]; pb.u[3] = pk[g][ss][3];
        const int u0 = 4*g + 2*ss;
        #pragma unroll
        for (int dg=0; dg<2; dg++){
          const int d = dg*32 + lq;
          union { u16x4 h[2]; bf16x8 v; } va;
          va.h[0] = *reinterpret_cast<const u16x4*>(
              &Vs[cb][d*64 + ((u0     ^ (d&7))*8) + hi*4]);
          va.h[1] = *reinterpret_cast<const u16x4*>(
              &Vs[cb][d*64 + (((u0+1) ^ (d&7))*8) + hi*4]);
          accO[dg] = MFMA32(va.v, pb.v, accO[dg]);
        }
      }
    }
    __builtin_amdgcn_s_setprio(0);

    if (w == 0 && c + 1 < 32)
      Ms[cb^1][l] = ((bits >> (c+1)) & 1u) ? -1e9f : 0.f;

    if (c < 31){
      asm volatile("s_waitcnt vmcnt(0) lgkmcnt(0)" ::: "memory");
      __builtin_amdgcn_s_barrier();
      asm volatile("" ::: "memory");
    }
  }

  {
    const int qrow = q0w + lq;
    const int qm = bm[qrow];
    const float inv = (qm || lsum <= 0.f) ? 0.f : 1.f / lsum;
    #pragma unroll
    for (int dg=0; dg<2; dg++)
      #pragma unroll
      for (int m=0; m<4; m++){
        ushort4 o;
        o.x = f2bf(accO[dg][4*m+0] * inv);
        o.y = f2bf(accO[dg][4*m+1] * inv);
        o.z = f2bf(accO[dg][4*m+2] * inv);
        o.w = f2bf(accO[dg][4*m+3] * inv);
        *reinterpret_cast<ushort4*>(
            &AO[(tokbase + qrow) * (size_t)Dc + h*64 + dg*32 + m*8 + hi*4]) = o;
      }
  }
}

// ---------- launch ----------
extern "C" void kernel_launch(void* const* d_in, const int* in_sizes, int n_in,
                              void* d_out, int out_size, void* d_ws, size_t ws_size,
                              hipStream_t stream){
  const float* h    = (const float*)d_in[0];
  const unsigned* m = (const unsigned*)d_in[1];
  const float* Wq   = (const float*)d_in[2];
  const float* Wk   = (const float*)d_in[3];
  const float* Wv   = (const float*)d_in[4];
  const float* Wo   = (const float*)d_in[5];
  float* out        = (float*)d_out;

  unsigned short* hb   = (unsigned short*)d_ws;       // 8192*768 (reused as VtG after gemm1)
  unsigned short* Wqkv = hb   + (size_t)NTOK * Dc;    // 2304*768
  unsigned short* Wob  = Wqkv + (size_t)QKV_LD * Dc;  // 768*768
  unsigned short* QKV  = Wob  + (size_t)Dc * Dc;      // 8192*2304
  unsigned short* AO   = QKV  + (size_t)NTOK * QKV_LD;// 8192*768
  int* mexp            = (int*)(AO + (size_t)NTOK * Dc);

  const size_t need = ((size_t)NTOK*Dc + (size_t)QKV_LD*Dc + (size_t)Dc*Dc +
                       (size_t)NTOK*QKV_LD + (size_t)NTOK*Dc) * 2 + (size_t)NTOK*4;
  if (ws_size < need) return;

  const int W2 = Dc * Dc;
  // Wq folded with (1/8)*log2e -> scores in log2 domain for exp2 softmax
  cvt_bf16<<<(NTOK*Dc/4 + 255)/256, 256, 0, stream>>>(h, hb, NTOK*Dc/4, 1.0f);
  cvt_w4<<<dim3((W2/4 + 255)/256, 4), 256, 0, stream>>>(
      Wq, Wk, Wv, Wo, Wqkv, Wob, W2/4, 0.125f*1.44269504f);
  expand_mask<<<1, 256, 0, stream>>>(m, mexp, NTOK);

  gemm_bt<unsigned short><<<dim3(QKV_LD/128, NTOK/128), 256, 0, stream>>>(
      hb, Wqkv, QKV, NTOK, QKV_LD, Dc);

  // V^T into the now-dead hb buffer
  unsigned short* VtG = hb;
  vtrans<<<dim3(Tc/64, Bc*Hc), 256, 0, stream>>>(QKV, VtG);

  attn<<<dim3(16, Bc*Hc), 256, 0, stream>>>(QKV, VtG, mexp, AO);

  gemm_bt64<<<dim3(Dc/128, NTOK/64), 256, 0, stream>>>(
      AO, Wob, out, NTOK, Dc, Dc);
}

// Round 12
// 174.553 us; speedup vs baseline: 1.2082x; 1.0243x over previous
//
#include <hip/hip_runtime.h>
#include <stdint.h>

// ---------- types ----------
typedef __bf16 bf16x8 __attribute__((ext_vector_type(8)));
typedef float  f32x4  __attribute__((ext_vector_type(4)));
typedef float  f32x16 __attribute__((ext_vector_type(16)));
typedef unsigned short u16x4 __attribute__((ext_vector_type(4)));

#define MFMA16(a,b,c) __builtin_amdgcn_mfma_f32_16x16x32_bf16((a),(b),(c),0,0,0)
#define MFMA32(a,b,c) __builtin_amdgcn_mfma_f32_32x32x16_bf16((a),(b),(c),0,0,0)

constexpr int Bc  = 4;
constexpr int Tc  = 2048;
constexpr int Dc  = 768;
constexpr int Hc  = 12;
constexpr int NTOK = Bc * Tc;        // 8192
constexpr int QKV_N = 3 * Dc;        // 2304 (gemm1 output columns)
constexpr int QK_LD = 2 * Dc;        // 1536 (QK-only buffer stride)

static __device__ __forceinline__ unsigned short f2bf(float f){
  unsigned u = __float_as_uint(f);
  u += 0x7fffu + ((u >> 16) & 1u);   // RNE
  return (unsigned short)(u >> 16);
}

static __device__ __forceinline__ float exp2a(float x){
  float r; asm("v_exp_f32 %0, %1" : "=v"(r) : "v"(x)); return r;
}

static __device__ __forceinline__ float max3f(float a, float b, float c){
  float r; asm("v_max3_f32 %0, %1, %2, %3" : "=v"(r) : "v"(a), "v"(b), "v"(c)); return r;
}

static __device__ __forceinline__ unsigned cvtpk_bf16(float lo, float hi){
  unsigned r; asm("v_cvt_pk_bf16_f32 %0, %1, %2" : "=v"(r) : "v"(lo), "v"(hi)); return r;
}

static __device__ __forceinline__ void gload_lds16(const void* g, void* l){
  __builtin_amdgcn_global_load_lds((__attribute__((address_space(1))) void*)g,
                                   (__attribute__((address_space(3))) void*)l,
                                   16, 0, 0);
}

// ---------- f32 -> bf16 conversion (h) ----------
__global__ void cvt_bf16(const float* __restrict__ src, unsigned short* __restrict__ dst,
                         int n4, float scale){
  int i = blockIdx.x * blockDim.x + threadIdx.x;
  if (i >= n4) return;
  float4 v = reinterpret_cast<const float4*>(src)[i];
  ushort4 o;
  o.x = f2bf(v.x * scale); o.y = f2bf(v.y * scale);
  o.z = f2bf(v.z * scale); o.w = f2bf(v.w * scale);
  reinterpret_cast<ushort4*>(dst)[i] = o;
}

// ---------- fused weight conversion: Wq(scaled)/Wk/Wv -> Wqkv, Wo -> Wob ----------
__global__ void cvt_w4(const float* __restrict__ Wq, const float* __restrict__ Wk,
                       const float* __restrict__ Wv, const float* __restrict__ Wo,
                       unsigned short* __restrict__ Wqkv, unsigned short* __restrict__ Wob,
                       int n4, float qscale){
  const int y = blockIdx.y;
  const float* src = (y==0) ? Wq : (y==1) ? Wk : (y==2) ? Wv : Wo;
  unsigned short* dst = (y==3) ? Wob : Wqkv + (size_t)y * n4 * 4;
  const float scale = (y==0) ? qscale : 1.0f;
  int i = blockIdx.x * blockDim.x + threadIdx.x;
  if (i >= n4) return;
  float4 v = reinterpret_cast<const float4*>(src)[i];
  ushort4 o;
  o.x = f2bf(v.x * scale); o.y = f2bf(v.y * scale);
  o.z = f2bf(v.z * scale); o.w = f2bf(v.w * scale);
  reinterpret_cast<ushort4*>(dst)[i] = o;
}

// ---------- mask expansion with layout auto-detection ----------
__global__ void expand_mask(const unsigned* __restrict__ raw, int* __restrict__ out, int n){
  __shared__ int sInt, sFlt;
  int t = threadIdx.x;
  if (t == 0){ sInt = 1; sFlt = 1; }
  __syncthreads();
  int okI = 1, okF = 1;
  for (int i = t; i < n/4; i += blockDim.x){
    unsigned u = raw[i];
    okI &= (u <= 1u);
    okF &= (u == 0u || u == 0x3f800000u);
  }
  if (!okI) atomicAnd(&sInt, 0);
  if (!okF) atomicAnd(&sFlt, 0);
  __syncthreads();
  if (sInt || sFlt){
    for (int i = t; i < n; i += blockDim.x) out[i] = (raw[i] != 0u);
  } else {
    const unsigned char* rb = (const unsigned char*)raw;
    for (int i = t; i < n; i += blockDim.x) out[i] = (rb[i] != 0);
  }
}

// ---------- gemm1: h @ Wqkv^T with fused V-transpose epilogue ----------
// C cols [0,1536)   -> QKt[tok][col]        (stride 1536, bf16)
// C cols [1536,2304)-> VtG[(b*H+h)*64+d][tok] (transposed, 8B packed stores)
// Block-uniform branch: bc multiples of 128; 1536/128 = 12 exact.
__global__ __launch_bounds__(256) void gemm_qkv(const unsigned short* __restrict__ A,
                                                const unsigned short* __restrict__ Bm,
                                                unsigned short* __restrict__ QKt,
                                                unsigned short* __restrict__ VtG,
                                                int M, int N, int K){
  __shared__ unsigned short As[128*32];
  __shared__ unsigned short Bs[128*32];
  const int t = threadIdx.x;
  const int w = t >> 6, l = t & 63;
  const int wr = w >> 1, wc = w & 1;
  const int br = blockIdx.y * 128, bc = blockIdx.x * 128;

  f32x4 acc[4][4];
  const f32x4 fz = {0.f,0.f,0.f,0.f};
  #pragma unroll
  for (int m=0;m<4;m++)
    #pragma unroll
    for (int n=0;n<4;n++) acc[m][n] = fz;

  const int lrow = l >> 2;
  const int lk   = (l & 3) * 8;
  const int fr   = l & 15;
  const int fk   = (l >> 4) * 8;

  for (int k0 = 0; k0 < K; k0 += 32){
    #pragma unroll
    for (int it = 0; it < 2; ++it){
      const int rb = it*64 + w*16;
      gload_lds16(A  + (size_t)(br + rb + lrow)*K + k0 + lk, &As[rb*32]);
      gload_lds16(Bm + (size_t)(bc + rb + lrow)*K + k0 + lk, &Bs[rb*32]);
    }
    __syncthreads();
    bf16x8 a[4], b[4];
    #pragma unroll
    for (int m=0;m<4;m++)
      a[m] = *reinterpret_cast<const bf16x8*>(&As[(wr*64 + m*16 + fr)*32 + fk]);
    #pragma unroll
    for (int n=0;n<4;n++)
      b[n] = *reinterpret_cast<const bf16x8*>(&Bs[(wc*64 + n*16 + fr)*32 + fk]);
    #pragma unroll
    for (int m=0;m<4;m++)
      #pragma unroll
      for (int n=0;n<4;n++)
        acc[m][n] = MFMA16(a[m], b[n], acc[m][n]);
    __syncthreads();
  }

  const int orow0 = br + wr*64 + (l >> 4)*4;
  const int ocol0 = bc + wc*64 + (l & 15);
  if (bc >= QK_LD){
    // V region: write transposed into VtG, 4 consecutive tokens per 8B store
    #pragma unroll
    for (int m=0;m<4;m++){
      const int orow = orow0 + m*16;
      const int bb = orow >> 11, tok = orow & 2047;
      #pragma unroll
      for (int n=0;n<4;n++){
        const int cc = ocol0 + n*16 - QK_LD;   // 0..767
        const int hh = cc >> 6, dd = cc & 63;
        ushort4 o;
        o.x = f2bf(acc[m][n][0]); o.y = f2bf(acc[m][n][1]);
        o.z = f2bf(acc[m][n][2]); o.w = f2bf(acc[m][n][3]);
        *reinterpret_cast<ushort4*>(
            &VtG[((size_t)((bb*Hc + hh)*64 + dd))*Tc + tok]) = o;
      }
    }
  } else {
    #pragma unroll
    for (int m=0;m<4;m++)
      #pragma unroll
      for (int n=0;n<4;n++)
        #pragma unroll
        for (int r=0;r<4;r++)
          QKt[(size_t)(orow0 + m*16 + r) * QK_LD + (ocol0 + n*16)] =
              f2bf(acc[m][n][r]);
  }
}

// ---------- bf16 NT GEMM 64x128 (out-proj, f32 out) ----------
__global__ __launch_bounds__(256) void gemm_bt64(const unsigned short* __restrict__ A,
                                                 const unsigned short* __restrict__ Bm,
                                                 float* __restrict__ C,
                                                 int M, int N, int K){
  __shared__ unsigned short As[64*32];
  __shared__ unsigned short Bs[128*32];
  const int t = threadIdx.x;
  const int w = t >> 6, l = t & 63;
  const int wr = w >> 1, wc = w & 1;
  const int br = blockIdx.y * 64, bc = blockIdx.x * 128;

  f32x4 acc[2][4];
  const f32x4 fz = {0.f,0.f,0.f,0.f};
  #pragma unroll
  for (int m=0;m<2;m++)
    #pragma unroll
    for (int n=0;n<4;n++) acc[m][n] = fz;

  const int lrow = l >> 2;
  const int lk   = (l & 3) * 8;
  const int fr   = l & 15;
  const int fk   = (l >> 4) * 8;

  for (int k0 = 0; k0 < K; k0 += 32){
    gload_lds16(A + (size_t)(br + w*16 + lrow)*K + k0 + lk, &As[(w*16)*32]);
    #pragma unroll
    for (int it = 0; it < 2; ++it){
      const int rb = it*64 + w*16;
      gload_lds16(Bm + (size_t)(bc + rb + lrow)*K + k0 + lk, &Bs[rb*32]);
    }
    __syncthreads();
    bf16x8 a[2], b[4];
    #pragma unroll
    for (int m=0;m<2;m++)
      a[m] = *reinterpret_cast<const bf16x8*>(&As[(wr*32 + m*16 + fr)*32 + fk]);
    #pragma unroll
    for (int n=0;n<4;n++)
      b[n] = *reinterpret_cast<const bf16x8*>(&Bs[(wc*64 + n*16 + fr)*32 + fk]);
    #pragma unroll
    for (int m=0;m<2;m++)
      #pragma unroll
      for (int n=0;n<4;n++)
        acc[m][n] = MFMA16(a[m], b[n], acc[m][n]);
    __syncthreads();
  }

  const int orow0 = br + wr*32 + (l >> 4)*4;
  const int ocol0 = bc + wc*64 + (l & 15);
  #pragma unroll
  for (int m=0;m<2;m++)
    #pragma unroll
    for (int n=0;n<4;n++)
      #pragma unroll
      for (int r=0;r<4;r++)
        C[(size_t)(orow0 + m*16 + r) * N + (ocol0 + n*16)] = acc[m][n][r];
}

// ---------- flash attention: 32x32 MFMA, Q=128/block, 2-buffer, XCD swizzle ----------
// (verified round 9/10: ~86.5us; Q/K now in QK-only buffer, stride 1536)
__global__ __launch_bounds__(256, 3) void attn(const unsigned short* __restrict__ QKt,
                                               const unsigned short* __restrict__ VtG,
                                               const int* __restrict__ mask,
                                               unsigned short* __restrict__ AO){
  __shared__ unsigned short Ks[2][64*64];  // K chunk, source-swizzled (16B units: c ^= row&7)
  __shared__ unsigned short Vs[2][64*64];  // V^T chunk [d][key], same source swizzle
  __shared__ float Ms[2][64];              // additive key-mask bias

  const int t = threadIdx.x, w = t >> 6, l = t & 63;
  const int lin = blockIdx.y * gridDim.x + blockIdx.x;   // 0..767
  const int swz = (lin & 7) * 96 + (lin >> 3);
  const int qt  = swz & 15;
  const int bh  = swz >> 4;
  const int b  = bh / Hc, h = bh - b * Hc;
  const int lq = l & 31, hi = l >> 5;
  const int q0w = qt * 128 + w * 32;

  const size_t tokbase = (size_t)b * Tc;
  const unsigned short* Qp = QKt + (tokbase + q0w) * (size_t)QK_LD + h*64;
  const unsigned short* Kbase = QKt + tokbase * (size_t)QK_LD + h*64 + 768;
  const unsigned short* VtB = VtG + (size_t)(bh*64) * Tc;
  const int* bm = mask + b * Tc;

  bf16x8 qa[4];
  #pragma unroll
  for (int s=0; s<4; s++)
    qa[s] = *reinterpret_cast<const bf16x8*>(
        Qp + (size_t)lq*QK_LD + s*16 + hi*8);

  unsigned bits = 0;
  if (w == 0){
    #pragma unroll
    for (int cc = 0; cc < 32; ++cc)
      bits |= (unsigned)(bm[cc*64 + l] != 0) << cc;
  }

  f32x16 accO[2];
  #pragma unroll
  for (int dg=0; dg<2; dg++)
    #pragma unroll
    for (int r=0; r<16; r++) accO[dg][r] = 0.f;
  float mrow = -1e30f, lsum = 0.f;

  const int srow = l >> 3, scol = (l & 7) ^ (l >> 3);   // source swizzle
  auto stage = [&](int c){
    const int key0 = c * 64, buf = c & 1;
    #pragma unroll
    for (int i=0; i<2; i++){
      const int rb = w*16 + i*8;      // K rows
      gload_lds16(Kbase + (size_t)(key0 + rb + srow)*QK_LD + scol*8,
                  &Ks[buf][rb*64]);
    }
    #pragma unroll
    for (int i=0; i<2; i++){
      const int rb = (w*2 + i)*8;     // V^T rows (d)
      gload_lds16(VtB + (size_t)(rb + srow)*Tc + key0 + scol*8,
                  &Vs[buf][rb*64]);
    }
  };

  stage(0);
  if (w == 0) Ms[0][l] = (bits & 1u) ? -1e9f : 0.f;
  asm volatile("s_waitcnt vmcnt(0) lgkmcnt(0)" ::: "memory");
  __builtin_amdgcn_s_barrier();
  asm volatile("" ::: "memory");

  #pragma unroll 2
  for (int c = 0; c < 32; ++c){
    const int cb = c & 1;

    f32x16 S[2];
    __builtin_amdgcn_s_setprio(1);
    #pragma unroll
    for (int g=0; g<2; g++){
      union { f32x4 q[4]; f32x16 v; } mi;
      #pragma unroll
      for (int m=0; m<4; m++)
        mi.q[m] = *reinterpret_cast<const f32x4*>(&Ms[cb][g*32 + m*8 + hi*4]);
      S[g] = mi.v;
      #pragma unroll
      for (int s=0; s<4; s++){
        const int row = g*32 + lq;
        bf16x8 kf = *reinterpret_cast<const bf16x8*>(
            &Ks[cb][row*64 + (((2*s + hi) ^ (row&7))*8)]);
        S[g] = MFMA32(kf, qa[s], S[g]);
      }
    }
    __builtin_amdgcn_s_setprio(0);

    if (c + 1 < 32) stage(c + 1);

    unsigned pk[2][2][4];
    {
      float m0 = max3f(S[0][0],  S[0][1],  S[0][2]);
      float m1 = max3f(S[0][3],  S[0][4],  S[0][5]);
      float m2 = max3f(S[0][6],  S[0][7],  S[0][8]);
      float m3 = max3f(S[0][9],  S[0][10], S[0][11]);
      float m4 = max3f(S[0][12], S[0][13], S[0][14]);
      float m5 = max3f(S[0][15], S[1][0],  S[1][1]);
      float m6 = max3f(S[1][2],  S[1][3],  S[1][4]);
      float m7 = max3f(S[1][5],  S[1][6],  S[1][7]);
      float m8 = max3f(S[1][8],  S[1][9],  S[1][10]);
      float m9 = max3f(S[1][11], S[1][12], S[1][13]);
      float ma = fmaxf(S[1][14], S[1][15]);
      float cm = max3f(max3f(m0,m1,m2), max3f(m3,m4,m5),
                       max3f(max3f(m6,m7,m8), m9, ma));
      cm = fmaxf(cm, __shfl_xor(cm, 32));
      if (!__all(cm <= mrow + 8.0f)){     // defer-max (T13)
        const float nm = fmaxf(mrow, cm);
        const float sc = exp2a(mrow - nm);
        lsum *= sc;
        #pragma unroll
        for (int dg=0; dg<2; dg++)
          #pragma unroll
          for (int r=0; r<16; r++) accO[dg][r] *= sc;
        mrow = nm;
      }
      float ps = 0.f;
      #pragma unroll
      for (int g=0; g<2; g++){
        float p[16];
        #pragma unroll
        for (int r=0; r<16; r++) p[r] = exp2a(S[g][r] - mrow);
        float t0 = (p[0]+p[1]) + (p[2]+p[3]);
        float t1 = (p[4]+p[5]) + (p[6]+p[7]);
        float t2 = (p[8]+p[9]) + (p[10]+p[11]);
        float t3 = (p[12]+p[13]) + (p[14]+p[15]);
        ps += (t0+t1) + (t2+t3);
        #pragma unroll
        for (int ss=0; ss<2; ss++)
          #pragma unroll
          for (int j2=0; j2<4; j2++)
            pk[g][ss][j2] = cvtpk_bf16(p[ss*8 + 2*j2], p[ss*8 + 2*j2 + 1]);
      }
      ps += __shfl_xor(ps, 32);
      lsum += ps;
    }

    __builtin_amdgcn_s_setprio(1);
    #pragma unroll
    for (int g=0; g<2; g++){
      #pragma unroll
      for (int ss=0; ss<2; ss++){
        union { unsigned u[4]; bf16x8 v; } pb;
        pb.u[0] = pk[g][ss][0]; pb.u[1] = pk[g][ss][1];
        pb.u[2] = pk[g][ss][2]; pb.u[3] = pk[g][ss][3];
        const int u0 = 4*g + 2*ss;
        #pragma unroll
        for (int dg=0; dg<2; dg++){
          const int d = dg*32 + lq;
          union { u16x4 h[2]; bf16x8 v; } va;
          va.h[0] = *reinterpret_cast<const u16x4*>(
              &Vs[cb][d*64 + ((u0     ^ (d&7))*8) + hi*4]);
          va.h[1] = *reinterpret_cast<const u16x4*>(
              &Vs[cb][d*64 + (((u0+1) ^ (d&7))*8) + hi*4]);
          accO[dg] = MFMA32(va.v, pb.v, accO[dg]);
        }
      }
    }
    __builtin_amdgcn_s_setprio(0);

    if (w == 0 && c + 1 < 32)
      Ms[cb^1][l] = ((bits >> (c+1)) & 1u) ? -1e9f : 0.f;

    if (c < 31){
      asm volatile("s_waitcnt vmcnt(0) lgkmcnt(0)" ::: "memory");
      __builtin_amdgcn_s_barrier();
      asm volatile("" ::: "memory");
    }
  }

  {
    const int qrow = q0w + lq;
    const int qm = bm[qrow];
    const float inv = (qm || lsum <= 0.f) ? 0.f : 1.f / lsum;
    #pragma unroll
    for (int dg=0; dg<2; dg++)
      #pragma unroll
      for (int m=0; m<4; m++){
        ushort4 o;
        o.x = f2bf(accO[dg][4*m+0] * inv);
        o.y = f2bf(accO[dg][4*m+1] * inv);
        o.z = f2bf(accO[dg][4*m+2] * inv);
        o.w = f2bf(accO[dg][4*m+3] * inv);
        *reinterpret_cast<ushort4*>(
            &AO[(tokbase + qrow) * (size_t)Dc + h*64 + dg*32 + m*8 + hi*4]) = o;
      }
  }
}

// ---------- launch ----------
extern "C" void kernel_launch(void* const* d_in, const int* in_sizes, int n_in,
                              void* d_out, int out_size, void* d_ws, size_t ws_size,
                              hipStream_t stream){
  const float* h    = (const float*)d_in[0];
  const unsigned* m = (const unsigned*)d_in[1];
  const float* Wq   = (const float*)d_in[2];
  const float* Wk   = (const float*)d_in[3];
  const float* Wv   = (const float*)d_in[4];
  const float* Wo   = (const float*)d_in[5];
  float* out        = (float*)d_out;

  unsigned short* hb   = (unsigned short*)d_ws;       // 8192*768
  unsigned short* Wqkv = hb   + (size_t)NTOK * Dc;    // 2304*768
  unsigned short* Wob  = Wqkv + (size_t)QKV_N * Dc;   // 768*768
  unsigned short* QKt  = Wob  + (size_t)Dc * Dc;      // 8192*1536 (Q|K)
  unsigned short* VtG  = QKt  + (size_t)NTOK * QK_LD; // 48*64 x 2048 (V^T)
  unsigned short* AO   = VtG  + (size_t)NTOK * Dc;    // 8192*768
  int* mexp            = (int*)(AO + (size_t)NTOK * Dc);

  const size_t need = ((size_t)NTOK*Dc + (size_t)QKV_N*Dc + (size_t)Dc*Dc +
                       (size_t)NTOK*QK_LD + (size_t)NTOK*Dc + (size_t)NTOK*Dc) * 2
                      + (size_t)NTOK*4;
  if (ws_size < need) return;

  const int W2 = Dc * Dc;
  // Wq folded with (1/8)*log2e -> scores in log2 domain for exp2 softmax
  cvt_bf16<<<(NTOK*Dc/4 + 255)/256, 256, 0, stream>>>(h, hb, NTOK*Dc/4, 1.0f);
  cvt_w4<<<dim3((W2/4 + 255)/256, 4), 256, 0, stream>>>(
      Wq, Wk, Wv, Wo, Wqkv, Wob, W2/4, 0.125f*1.44269504f);
  expand_mask<<<1, 256, 0, stream>>>(m, mexp, NTOK);

  // fused QKV projection; V written transposed straight into VtG
  gemm_qkv<<<dim3(QKV_N/128, NTOK/128), 256, 0, stream>>>(
      hb, Wqkv, QKt, VtG, NTOK, QKV_N, Dc);

  attn<<<dim3(16, Bc*Hc), 256, 0, stream>>>(QKt, VtG, mexp, AO);

  gemm_bt64<<<dim3(Dc/128, NTOK/64), 256, 0, stream>>>(
      AO, Wob, out, NTOK, Dc, Dc);
}

// Round 13
// 170.227 us; speedup vs baseline: 1.2389x; 1.0254x over previous
//
#include <hip/hip_runtime.h>
#include <stdint.h>

// ---------- types ----------
typedef __bf16 bf16x8 __attribute__((ext_vector_type(8)));
typedef float  f32x4  __attribute__((ext_vector_type(4)));
typedef float  f32x16 __attribute__((ext_vector_type(16)));
typedef unsigned short u16x4 __attribute__((ext_vector_type(4)));

#define MFMA16(a,b,c) __builtin_amdgcn_mfma_f32_16x16x32_bf16((a),(b),(c),0,0,0)
#define MFMA32(a,b,c) __builtin_amdgcn_mfma_f32_32x32x16_bf16((a),(b),(c),0,0,0)

constexpr int Bc  = 4;
constexpr int Tc  = 2048;
constexpr int Dc  = 768;
constexpr int Hc  = 12;
constexpr int NTOK = Bc * Tc;        // 8192
constexpr int QKV_N = 3 * Dc;        // 2304 (gemm1 output columns)
constexpr int QK_LD = 2 * Dc;        // 1536 (QK-only buffer stride)
constexpr int H4 = NTOK * Dc / 4;    // 1572864 float4 of h
constexpr int W4 = Dc * Dc / 4;      // 147456 float4 per weight

static __device__ __forceinline__ unsigned short f2bf(float f){
  unsigned u = __float_as_uint(f);
  u += 0x7fffu + ((u >> 16) & 1u);   // RNE
  return (unsigned short)(u >> 16);
}

static __device__ __forceinline__ float exp2a(float x){
  float r; asm("v_exp_f32 %0, %1" : "=v"(r) : "v"(x)); return r;
}

static __device__ __forceinline__ float max3f(float a, float b, float c){
  float r; asm("v_max3_f32 %0, %1, %2, %3" : "=v"(r) : "v"(a), "v"(b), "v"(c)); return r;
}

static __device__ __forceinline__ unsigned cvtpk_bf16(float lo, float hi){
  unsigned r; asm("v_cvt_pk_bf16_f32 %0, %1, %2" : "=v"(r) : "v"(lo), "v"(hi)); return r;
}

static __device__ __forceinline__ void gload_lds16(const void* g, void* l){
  __builtin_amdgcn_global_load_lds((__attribute__((address_space(1))) void*)g,
                                   (__attribute__((address_space(3))) void*)l,
                                   16, 0, 0);
}

// ---------- fused f32->bf16 conversion: h + 4 weights in one dispatch ----------
__global__ void prep(const float* __restrict__ h,  const float* __restrict__ Wq,
                     const float* __restrict__ Wk, const float* __restrict__ Wv,
                     const float* __restrict__ Wo,
                     unsigned short* __restrict__ hb,
                     unsigned short* __restrict__ Wqkv,
                     unsigned short* __restrict__ Wob, float qscale){
  const int idx = blockIdx.x * blockDim.x + threadIdx.x;
  const float* src; ushort4* dst; float sc = 1.0f; int r;
  if (idx < H4){
    src = h; dst = reinterpret_cast<ushort4*>(hb); r = idx;
  } else {
    const int j = idx - H4;
    const int y = j / W4;
    r = j - y * W4;
    if (y == 0){ src = Wq; sc = qscale; } else if (y == 1){ src = Wk; }
    else if (y == 2){ src = Wv; } else { src = Wo; }
    dst = (y == 3) ? reinterpret_cast<ushort4*>(Wob)
                   : reinterpret_cast<ushort4*>(Wqkv) + (size_t)y * W4;
  }
  float4 v = reinterpret_cast<const float4*>(src)[r];
  ushort4 o;
  o.x = f2bf(v.x * sc); o.y = f2bf(v.y * sc);
  o.z = f2bf(v.z * sc); o.w = f2bf(v.w * sc);
  dst[r] = o;
}

// ---------- mask expansion with layout auto-detection ----------
__global__ void expand_mask(const unsigned* __restrict__ raw, int* __restrict__ out, int n){
  __shared__ int sInt, sFlt;
  int t = threadIdx.x;
  if (t == 0){ sInt = 1; sFlt = 1; }
  __syncthreads();
  int okI = 1, okF = 1;
  for (int i = t; i < n/4; i += blockDim.x){
    unsigned u = raw[i];
    okI &= (u <= 1u);
    okF &= (u == 0u || u == 0x3f800000u);
  }
  if (!okI) atomicAnd(&sInt, 0);
  if (!okF) atomicAnd(&sFlt, 0);
  __syncthreads();
  if (sInt || sFlt){
    for (int i = t; i < n; i += blockDim.x) out[i] = (raw[i] != 0u);
  } else {
    const unsigned char* rb = (const unsigned char*)raw;
    for (int i = t; i < n; i += blockDim.x) out[i] = (rb[i] != 0);
  }
}

// ---------- gemm1: h @ Wqkv^T, BK=64, XOR-swizzled LDS, XCD swizzle ----------
// C cols [0,1536)   -> QKt[tok][col]
// C cols [1536,2304)-> VtG[(b*H+h)*64+d][tok] (transposed, 8B packed stores)
__global__ __launch_bounds__(256) void gemm_qkv(const unsigned short* __restrict__ A,
                                                const unsigned short* __restrict__ Bm,
                                                unsigned short* __restrict__ QKt,
                                                unsigned short* __restrict__ VtG,
                                                int M, int N, int K){
  __shared__ unsigned short As[128*64];
  __shared__ unsigned short Bs[128*64];
  const int t = threadIdx.x;
  const int w = t >> 6, l = t & 63;
  const int wr = w >> 1, wc = w & 1;
  // bijective XCD swizzle over 1152 blocks (1152%8==0): row-tile grouping
  const int lin = blockIdx.y * gridDim.x + blockIdx.x;   // 0..1151
  const int swz = (lin & 7) * 144 + (lin >> 3);
  const int bxs = swz % 18, bys = swz / 18;
  const int br = bys * 128, bc = bxs * 128;

  f32x4 acc[4][4];
  const f32x4 fz = {0.f,0.f,0.f,0.f};
  #pragma unroll
  for (int m=0;m<4;m++)
    #pragma unroll
    for (int n=0;n<4;n++) acc[m][n] = fz;

  const int srow = l >> 3;             // 0..7
  const int scol = (l & 7) ^ srow;     // source 16B-unit (pre-swizzle, rule #21)
  const int fr = l & 15;
  const int fu = l >> 4;               // 0..3 fragment 16B-unit

  for (int k0 = 0; k0 < K; k0 += 64){
    #pragma unroll
    for (int i = 0; i < 4; ++i){
      const int rb = w*32 + i*8;
      gload_lds16(A  + (size_t)(br + rb + srow)*K + k0 + scol*8, &As[rb*64]);
      gload_lds16(Bm + (size_t)(bc + rb + srow)*K + k0 + scol*8, &Bs[rb*64]);
    }
    __syncthreads();
    bf16x8 a[2][4], b[2][4];
    #pragma unroll
    for (int ks=0; ks<2; ks++){
      #pragma unroll
      for (int m=0;m<4;m++){
        const int row = wr*64 + m*16 + fr;
        a[ks][m] = *reinterpret_cast<const bf16x8*>(
            &As[row*64 + (((ks*4+fu) ^ (row&7))*8)]);
      }
      #pragma unroll
      for (int n=0;n<4;n++){
        const int row = wc*64 + n*16 + fr;
        b[ks][n] = *reinterpret_cast<const bf16x8*>(
            &Bs[row*64 + (((ks*4+fu) ^ (row&7))*8)]);
      }
    }
    #pragma unroll
    for (int ks=0; ks<2; ks++)
      #pragma unroll
      for (int m=0;m<4;m++)
        #pragma unroll
        for (int n=0;n<4;n++)
          acc[m][n] = MFMA16(a[ks][m], b[ks][n], acc[m][n]);
    __syncthreads();
  }

  const int orow0 = br + wr*64 + (l >> 4)*4;
  const int ocol0 = bc + wc*64 + (l & 15);
  if (bc >= QK_LD){
    // V region: write transposed into VtG, 4 consecutive tokens per 8B store
    #pragma unroll
    for (int m=0;m<4;m++){
      const int orow = orow0 + m*16;
      const int bb = orow >> 11, tok = orow & 2047;
      #pragma unroll
      for (int n=0;n<4;n++){
        const int cc = ocol0 + n*16 - QK_LD;   // 0..767
        const int hh = cc >> 6, dd = cc & 63;
        ushort4 o;
        o.x = f2bf(acc[m][n][0]); o.y = f2bf(acc[m][n][1]);
        o.z = f2bf(acc[m][n][2]); o.w = f2bf(acc[m][n][3]);
        *reinterpret_cast<ushort4*>(
            &VtG[((size_t)((bb*Hc + hh)*64 + dd))*Tc + tok]) = o;
      }
    }
  } else {
    #pragma unroll
    for (int m=0;m<4;m++)
      #pragma unroll
      for (int n=0;n<4;n++)
        #pragma unroll
        for (int r=0;r<4;r++)
          QKt[(size_t)(orow0 + m*16 + r) * QK_LD + (ocol0 + n*16)] =
              f2bf(acc[m][n][r]);
  }
}

// ---------- bf16 NT GEMM 64x128 (out-proj, f32 out) + XCD swizzle ----------
__global__ __launch_bounds__(256) void gemm_bt64(const unsigned short* __restrict__ A,
                                                 const unsigned short* __restrict__ Bm,
                                                 float* __restrict__ C,
                                                 int M, int N, int K){
  __shared__ unsigned short As[64*32];
  __shared__ unsigned short Bs[128*32];
  const int t = threadIdx.x;
  const int w = t >> 6, l = t & 63;
  const int wr = w >> 1, wc = w & 1;
  const int lin = blockIdx.y * gridDim.x + blockIdx.x;   // 0..767
  const int swz = (lin & 7) * 96 + (lin >> 3);
  const int bxs = swz % 6, bys = swz / 6;
  const int br = bys * 64, bc = bxs * 128;

  f32x4 acc[2][4];
  const f32x4 fz = {0.f,0.f,0.f,0.f};
  #pragma unroll
  for (int m=0;m<2;m++)
    #pragma unroll
    for (int n=0;n<4;n++) acc[m][n] = fz;

  const int lrow = l >> 2;
  const int lk   = (l & 3) * 8;
  const int fr   = l & 15;
  const int fk   = (l >> 4) * 8;

  for (int k0 = 0; k0 < K; k0 += 32){
    gload_lds16(A + (size_t)(br + w*16 + lrow)*K + k0 + lk, &As[(w*16)*32]);
    #pragma unroll
    for (int it = 0; it < 2; ++it){
      const int rb = it*64 + w*16;
      gload_lds16(Bm + (size_t)(bc + rb + lrow)*K + k0 + lk, &Bs[rb*32]);
    }
    __syncthreads();
    bf16x8 a[2], b[4];
    #pragma unroll
    for (int m=0;m<2;m++)
      a[m] = *reinterpret_cast<const bf16x8*>(&As[(wr*32 + m*16 + fr)*32 + fk]);
    #pragma unroll
    for (int n=0;n<4;n++)
      b[n] = *reinterpret_cast<const bf16x8*>(&Bs[(wc*64 + n*16 + fr)*32 + fk]);
    #pragma unroll
    for (int m=0;m<2;m++)
      #pragma unroll
      for (int n=0;n<4;n++)
        acc[m][n] = MFMA16(a[m], b[n], acc[m][n]);
    __syncthreads();
  }

  const int orow0 = br + wr*32 + (l >> 4)*4;
  const int ocol0 = bc + wc*64 + (l & 15);
  #pragma unroll
  for (int m=0;m<2;m++)
    #pragma unroll
    for (int n=0;n<4;n++)
      #pragma unroll
      for (int r=0;r<4;r++)
        C[(size_t)(orow0 + m*16 + r) * N + (ocol0 + n*16)] = acc[m][n][r];
}

// ---------- flash attention: 32x32 MFMA, Q=128/block, 2-buffer, XCD swizzle ----------
// (verified rounds 9-12: ~87us; UNCHANGED this round)
__global__ __launch_bounds__(256, 3) void attn(const unsigned short* __restrict__ QKt,
                                               const unsigned short* __restrict__ VtG,
                                               const int* __restrict__ mask,
                                               unsigned short* __restrict__ AO){
  __shared__ unsigned short Ks[2][64*64];  // K chunk, source-swizzled (16B units: c ^= row&7)
  __shared__ unsigned short Vs[2][64*64];  // V^T chunk [d][key], same source swizzle
  __shared__ float Ms[2][64];              // additive key-mask bias

  const int t = threadIdx.x, w = t >> 6, l = t & 63;
  const int lin = blockIdx.y * gridDim.x + blockIdx.x;   // 0..767
  const int swz = (lin & 7) * 96 + (lin >> 3);
  const int qt  = swz & 15;
  const int bh  = swz >> 4;
  const int b  = bh / Hc, h = bh - b * Hc;
  const int lq = l & 31, hi = l >> 5;
  const int q0w = qt * 128 + w * 32;

  const size_t tokbase = (size_t)b * Tc;
  const unsigned short* Qp = QKt + (tokbase + q0w) * (size_t)QK_LD + h*64;
  const unsigned short* Kbase = QKt + tokbase * (size_t)QK_LD + h*64 + 768;
  const unsigned short* VtB = VtG + (size_t)(bh*64) * Tc;
  const int* bm = mask + b * Tc;

  bf16x8 qa[4];
  #pragma unroll
  for (int s=0; s<4; s++)
    qa[s] = *reinterpret_cast<const bf16x8*>(
        Qp + (size_t)lq*QK_LD + s*16 + hi*8);

  unsigned bits = 0;
  if (w == 0){
    #pragma unroll
    for (int cc = 0; cc < 32; ++cc)
      bits |= (unsigned)(bm[cc*64 + l] != 0) << cc;
  }

  f32x16 accO[2];
  #pragma unroll
  for (int dg=0; dg<2; dg++)
    #pragma unroll
    for (int r=0; r<16; r++) accO[dg][r] = 0.f;
  float mrow = -1e30f, lsum = 0.f;

  const int srow = l >> 3, scol = (l & 7) ^ (l >> 3);   // source swizzle
  auto stage = [&](int c){
    const int key0 = c * 64, buf = c & 1;
    #pragma unroll
    for (int i=0; i<2; i++){
      const int rb = w*16 + i*8;      // K rows
      gload_lds16(Kbase + (size_t)(key0 + rb + srow)*QK_LD + scol*8,
                  &Ks[buf][rb*64]);
    }
    #pragma unroll
    for (int i=0; i<2; i++){
      const int rb = (w*2 + i)*8;     // V^T rows (d)
      gload_lds16(VtB + (size_t)(rb + srow)*Tc + key0 + scol*8,
                  &Vs[buf][rb*64]);
    }
  };

  stage(0);
  if (w == 0) Ms[0][l] = (bits & 1u) ? -1e9f : 0.f;
  asm volatile("s_waitcnt vmcnt(0) lgkmcnt(0)" ::: "memory");
  __builtin_amdgcn_s_barrier();
  asm volatile("" ::: "memory");

  #pragma unroll 2
  for (int c = 0; c < 32; ++c){
    const int cb = c & 1;

    f32x16 S[2];
    __builtin_amdgcn_s_setprio(1);
    #pragma unroll
    for (int g=0; g<2; g++){
      union { f32x4 q[4]; f32x16 v; } mi;
      #pragma unroll
      for (int m=0; m<4; m++)
        mi.q[m] = *reinterpret_cast<const f32x4*>(&Ms[cb][g*32 + m*8 + hi*4]);
      S[g] = mi.v;
      #pragma unroll
      for (int s=0; s<4; s++){
        const int row = g*32 + lq;
        bf16x8 kf = *reinterpret_cast<const bf16x8*>(
            &Ks[cb][row*64 + (((2*s + hi) ^ (row&7))*8)]);
        S[g] = MFMA32(kf, qa[s], S[g]);
      }
    }
    __builtin_amdgcn_s_setprio(0);

    if (c + 1 < 32) stage(c + 1);

    unsigned pk[2][2][4];
    {
      float m0 = max3f(S[0][0],  S[0][1],  S[0][2]);
      float m1 = max3f(S[0][3],  S[0][4],  S[0][5]);
      float m2 = max3f(S[0][6],  S[0][7],  S[0][8]);
      float m3 = max3f(S[0][9],  S[0][10], S[0][11]);
      float m4 = max3f(S[0][12], S[0][13], S[0][14]);
      float m5 = max3f(S[0][15], S[1][0],  S[1][1]);
      float m6 = max3f(S[1][2],  S[1][3],  S[1][4]);
      float m7 = max3f(S[1][5],  S[1][6],  S[1][7]);
      float m8 = max3f(S[1][8],  S[1][9],  S[1][10]);
      float m9 = max3f(S[1][11], S[1][12], S[1][13]);
      float ma = fmaxf(S[1][14], S[1][15]);
      float cm = max3f(max3f(m0,m1,m2), max3f(m3,m4,m5),
                       max3f(max3f(m6,m7,m8), m9, ma));
      cm = fmaxf(cm, __shfl_xor(cm, 32));
      if (!__all(cm <= mrow + 8.0f)){     // defer-max (T13)
        const float nm = fmaxf(mrow, cm);
        const float sc = exp2a(mrow - nm);
        lsum *= sc;
        #pragma unroll
        for (int dg=0; dg<2; dg++)
          #pragma unroll
          for (int r=0; r<16; r++) accO[dg][r] *= sc;
        mrow = nm;
      }
      float ps = 0.f;
      #pragma unroll
      for (int g=0; g<2; g++){
        float p[16];
        #pragma unroll
        for (int r=0; r<16; r++) p[r] = exp2a(S[g][r] - mrow);
        float t0 = (p[0]+p[1]) + (p[2]+p[3]);
        float t1 = (p[4]+p[5]) + (p[6]+p[7]);
        float t2 = (p[8]+p[9]) + (p[10]+p[11]);
        float t3 = (p[12]+p[13]) + (p[14]+p[15]);
        ps += (t0+t1) + (t2+t3);
        #pragma unroll
        for (int ss=0; ss<2; ss++)
          #pragma unroll
          for (int j2=0; j2<4; j2++)
            pk[g][ss][j2] = cvtpk_bf16(p[ss*8 + 2*j2], p[ss*8 + 2*j2 + 1]);
      }
      ps += __shfl_xor(ps, 32);
      lsum += ps;
    }

    __builtin_amdgcn_s_setprio(1);
    #pragma unroll
    for (int g=0; g<2; g++){
      #pragma unroll
      for (int ss=0; ss<2; ss++){
        union { unsigned u[4]; bf16x8 v; } pb;
        pb.u[0] = pk[g][ss][0]; pb.u[1] = pk[g][ss][1];
        pb.u[2] = pk[g][ss][2]; pb.u[3] = pk[g][ss][3];
        const int u0 = 4*g + 2*ss;
        #pragma unroll
        for (int dg=0; dg<2; dg++){
          const int d = dg*32 + lq;
          union { u16x4 h[2]; bf16x8 v; } va;
          va.h[0] = *reinterpret_cast<const u16x4*>(
              &Vs[cb][d*64 + ((u0     ^ (d&7))*8) + hi*4]);
          va.h[1] = *reinterpret_cast<const u16x4*>(
              &Vs[cb][d*64 + (((u0+1) ^ (d&7))*8) + hi*4]);
          accO[dg] = MFMA32(va.v, pb.v, accO[dg]);
        }
      }
    }
    __builtin_amdgcn_s_setprio(0);

    if (w == 0 && c + 1 < 32)
      Ms[cb^1][l] = ((bits >> (c+1)) & 1u) ? -1e9f : 0.f;

    if (c < 31){
      asm volatile("s_waitcnt vmcnt(0) lgkmcnt(0)" ::: "memory");
      __builtin_amdgcn_s_barrier();
      asm volatile("" ::: "memory");
    }
  }

  {
    const int qrow = q0w + lq;
    const int qm = bm[qrow];
    const float inv = (qm || lsum <= 0.f) ? 0.f : 1.f / lsum;
    #pragma unroll
    for (int dg=0; dg<2; dg++)
      #pragma unroll
      for (int m=0; m<4; m++){
        ushort4 o;
        o.x = f2bf(accO[dg][4*m+0] * inv);
        o.y = f2bf(accO[dg][4*m+1] * inv);
        o.z = f2bf(accO[dg][4*m+2] * inv);
        o.w = f2bf(accO[dg][4*m+3] * inv);
        *reinterpret_cast<ushort4*>(
            &AO[(tokbase + qrow) * (size_t)Dc + h*64 + dg*32 + m*8 + hi*4]) = o;
      }
  }
}

// ---------- launch ----------
extern "C" void kernel_launch(void* const* d_in, const int* in_sizes, int n_in,
                              void* d_out, int out_size, void* d_ws, size_t ws_size,
                              hipStream_t stream){
  const float* h    = (const float*)d_in[0];
  const unsigned* m = (const unsigned*)d_in[1];
  const float* Wq   = (const float*)d_in[2];
  const float* Wk   = (const float*)d_in[3];
  const float* Wv   = (const float*)d_in[4];
  const float* Wo   = (const float*)d_in[5];
  float* out        = (float*)d_out;

  unsigned short* hb   = (unsigned short*)d_ws;       // 8192*768
  unsigned short* Wqkv = hb   + (size_t)NTOK * Dc;    // 2304*768
  unsigned short* Wob  = Wqkv + (size_t)QKV_N * Dc;   // 768*768
  unsigned short* QKt  = Wob  + (size_t)Dc * Dc;      // 8192*1536 (Q|K)
  unsigned short* VtG  = QKt  + (size_t)NTOK * QK_LD; // 48*64 x 2048 (V^T)
  unsigned short* AO   = VtG  + (size_t)NTOK * Dc;    // 8192*768
  int* mexp            = (int*)(AO + (size_t)NTOK * Dc);

  const size_t need = ((size_t)NTOK*Dc + (size_t)QKV_N*Dc + (size_t)Dc*Dc +
                       (size_t)NTOK*QK_LD + (size_t)NTOK*Dc + (size_t)NTOK*Dc) * 2
                      + (size_t)NTOK*4;
  if (ws_size < need) return;

  // fused conversions: h + Wq(scaled by log2e/8) + Wk + Wv + Wo
  prep<<<(H4 + 4*W4 + 255)/256, 256, 0, stream>>>(
      h, Wq, Wk, Wv, Wo, hb, Wqkv, Wob, 0.125f*1.44269504f);
  expand_mask<<<1, 256, 0, stream>>>(m, mexp, NTOK);

  // fused QKV projection (BK=64); V written transposed straight into VtG
  gemm_qkv<<<dim3(QKV_N/128, NTOK/128), 256, 0, stream>>>(
      hb, Wqkv, QKt, VtG, NTOK, QKV_N, Dc);

  attn<<<dim3(16, Bc*Hc), 256, 0, stream>>>(QKt, VtG, mexp, AO);

  gemm_bt64<<<dim3(Dc/128, NTOK/64), 256, 0, stream>>>(
      AO, Wob, out, NTOK, Dc, Dc);
}